// Round 1
// baseline (1672.521 us; speedup 1.0000x reference)
//
#include <hip/hip_runtime.h>
#include <cstdint>
#include <cstddef>

#define BB 4
#define LL 1024
#define HH 768
#define AA 12
#define EE 32
#define PP 992          // EE*(EE-1)
#define NN (BB*PP)      // 3968
#define RR 97
#define GG 12           // HH/64

__device__ __forceinline__ void pair_decode(int p, int& i0, int& i1) {
    i0 = p / 31;
    int r = p - i0 * 31;
    i1 = r + (r >= i0 ? 1 : 0);
}

// ---------------------------------------------------------------------------
// K0: per (b,e): ent_feat[b,e,:] = 0.5*(hid[hd]+hid[tl])
//     ent_attn[b,e,:] = (0.5/A) * sum_a (att[b,a,hd,:] + att[b,a,tl,:])
// Only gathers the <=64 attention rows actually used (12.6 MB, not 192 MB).
// ---------------------------------------------------------------------------
__global__ __launch_bounds__(256) void k_ent_prep(
        const float* __restrict__ hid, const float* __restrict__ att,
        const int* __restrict__ head, const int* __restrict__ tail,
        float* __restrict__ ent_feat, float* __restrict__ ent_attn) {
    int be = blockIdx.x;         // b*EE + e
    int b  = be >> 5;
    int hd = head[be];
    int tl = tail[be];

    const float* hrow = hid + ((size_t)b * LL + hd) * HH;
    const float* trow = hid + ((size_t)b * LL + tl) * HH;
    for (int hh = threadIdx.x; hh < HH; hh += 256)
        ent_feat[(size_t)be * HH + hh] = 0.5f * (hrow[hh] + trow[hh]);

    const float* abase = att + (size_t)b * AA * LL * LL;
    for (int l = threadIdx.x; l < LL; l += 256) {
        float s = 0.f;
        #pragma unroll
        for (int a = 0; a < AA; ++a) {
            const float* ar = abase + (size_t)a * LL * LL;
            s += ar[(size_t)hd * LL + l] + ar[(size_t)tl * LL + l];
        }
        ent_attn[(size_t)be * LL + l] = s * (0.5f / AA);
    }
}

// ---------------------------------------------------------------------------
// K1: inv_s[b,p] = 1 / (sum_l e0[l]*e1[l]*am[l] + 1e-20)
// ---------------------------------------------------------------------------
__global__ __launch_bounds__(256) void k_pair_inv(
        const float* __restrict__ ent_attn, const float* __restrict__ am,
        float* __restrict__ inv_s) {
    int bp = blockIdx.x;
    int b = bp / PP, p = bp - b * PP;
    int i0, i1; pair_decode(p, i0, i1);
    const float* e0  = ent_attn + ((size_t)b * EE + i0) * LL;
    const float* e1  = ent_attn + ((size_t)b * EE + i1) * LL;
    const float* amr = am + (size_t)b * LL;
    float s = 0.f;
    for (int l = threadIdx.x; l < LL; l += 256)
        s += e0[l] * e1[l] * amr[l];
    #pragma unroll
    for (int off = 32; off > 0; off >>= 1) s += __shfl_down(s, off, 64);
    __shared__ float red[4];
    int lane = threadIdx.x & 63, w = threadIdx.x >> 6;
    if (lane == 0) red[w] = s;
    __syncthreads();
    if (threadIdx.x == 0) {
        float t = red[0] + red[1] + red[2] + red[3];
        inv_s[bp] = 1.0f / (t + 1e-20f);
    }
}

// ---------------------------------------------------------------------------
// K2: ht_info[b,p,:] = inv_s[b,p] * sum_l (e0[l]*e1[l]*am[l]) * hid[b,l,:]
// Tile: 32 pairs x 128 cols, K-step 32. Weights built on the fly from the
// 32-entity ent_attn tile in LDS (all pairs share the same 32 rows).
// ---------------------------------------------------------------------------
__global__ __launch_bounds__(256) void k_ht_info(
        const float* __restrict__ hid, const float* __restrict__ ent_attn,
        const float* __restrict__ am, const float* __restrict__ inv_s,
        float* __restrict__ ht_info) {
    int b  = blockIdx.z;
    int p0 = blockIdx.y * 32;
    int c0 = blockIdx.x * 128;

    __shared__ float ea[EE][36];     // [entity][l-chunk], padded, 16B-aligned rows
    __shared__ float ams[32];
    __shared__ float hs[32][132];    // [l-chunk][cols], padded

    int tid = threadIdx.x;
    int px = tid >> 5;               // pair group 0..7 (4 pairs each)
    int cx = tid & 31;               // col group 0..31 (4 cols each)

    int i0[4], i1[4]; float inv[4];
    #pragma unroll
    for (int pp = 0; pp < 4; ++pp) {
        int p = p0 + px * 4 + pp;
        pair_decode(p, i0[pp], i1[pp]);
        inv[pp] = inv_s[b * PP + p];
    }

    float4 acc[4] = {};

    for (int l0 = 0; l0 < LL; l0 += 32) {
        __syncthreads();
        {   // stage ent_attn chunk: 32 entities x 32 l
            int q = tid * 4;
            int ll = q & 31, ee = q >> 5;
            float4 v = *(const float4*)(ent_attn + ((size_t)b * EE + ee) * LL + l0 + ll);
            *(float4*)(&ea[ee][ll]) = v;
        }
        if (tid < 32) ams[tid] = am[(size_t)b * LL + l0 + tid];
        #pragma unroll
        for (int it = 0; it < 4; ++it) {   // stage hid chunk: 32 l x 128 cols
            int q = (tid + it * 256) * 4;
            int cc = q & 127, ll = q >> 7;
            float4 v = *(const float4*)(hid + ((size_t)b * LL + l0 + ll) * HH + c0 + cc);
            *(float4*)(&hs[ll][cc]) = v;
        }
        __syncthreads();
        #pragma unroll
        for (int l = 0; l < 32; ++l) {
            float amv = ams[l];
            float4 hv = *(const float4*)(&hs[l][cx * 4]);
            #pragma unroll
            for (int pp = 0; pp < 4; ++pp) {
                float wgt = ea[i0[pp]][l] * ea[i1[pp]][l] * amv;
                acc[pp].x += wgt * hv.x;
                acc[pp].y += wgt * hv.y;
                acc[pp].z += wgt * hv.z;
                acc[pp].w += wgt * hv.w;
            }
        }
    }

    #pragma unroll
    for (int pp = 0; pp < 4; ++pp) {
        int p = p0 + px * 4 + pp;
        float4 o;
        o.x = acc[pp].x * inv[pp];
        o.y = acc[pp].y * inv[pp];
        o.z = acc[pp].z * inv[pp];
        o.w = acc[pp].w * inv[pp];
        *(float4*)(ht_info + ((size_t)(b * PP + p)) * HH + c0 + cx * 4) = o;
    }
}

// ---------------------------------------------------------------------------
// K3: out[n,:] = tanh(concat(ent_feat[ent(n)], ht_info[n]) @ W + bias)
// M=3968, K=1536, Ncols=768.  64x64 tile, K-step 16, 4x4 per thread.
// WHICH=0 -> head entity (hts0), WHICH=1 -> tail entity (hts1).
// ---------------------------------------------------------------------------
template <int WHICH>
__global__ __launch_bounds__(256) void k_proj(
        const float* __restrict__ ent_feat, const float* __restrict__ ht_info,
        const float* __restrict__ W, const float* __restrict__ bias,
        float* __restrict__ out) {
    int m0 = blockIdx.y * 64;
    int c0 = blockIdx.x * 64;

    __shared__ float As[64][20];   // [m][k] pad->80B rows (16B aligned)
    __shared__ float Bs[16][68];   // [k][c] pad->272B rows (16B aligned)

    int tid = threadIdx.x;
    int tx = tid & 15;             // col group: cols c0 + tx*4 .. +3
    int ty = tid >> 4;             // row group: rows m0 + ty*4 .. +3

    // staging indices (fixed per thread)
    int qa = tid * 4;
    int akk = qa & 15, amm = qa >> 4;       // A: row amm, k = akk..akk+3
    int qb = tid * 4;
    int bcc = qb & 63, bkk = qb >> 6;       // B: k-row bkk, cols bcc..bcc+3

    // gathered A-row source pointers for row m0+amm
    int n_a = m0 + amm;
    int b_a = n_a / PP, p_a = n_a - b_a * PP;
    int ia0, ia1; pair_decode(p_a, ia0, ia1);
    int ent = (WHICH == 0) ? ia0 : ia1;
    const float* featrow = ent_feat + ((size_t)(b_a * EE + ent)) * HH;
    const float* htrow   = ht_info + ((size_t)(b_a * PP + p_a)) * HH;

    float4 acc[4] = {};

    for (int k0 = 0; k0 < 2 * HH; k0 += 16) {
        __syncthreads();
        {
            const float* src = (k0 < HH) ? (featrow + k0 + akk)
                                         : (htrow + (k0 - HH) + akk);
            float4 v = *(const float4*)src;
            *(float4*)(&As[amm][akk]) = v;
        }
        {
            float4 v = *(const float4*)(W + (size_t)(k0 + bkk) * HH + c0 + bcc);
            *(float4*)(&Bs[bkk][bcc]) = v;
        }
        __syncthreads();
        #pragma unroll
        for (int kk = 0; kk < 16; ++kk) {
            float4 bv = *(const float4*)(&Bs[kk][tx * 4]);
            #pragma unroll
            for (int mi = 0; mi < 4; ++mi) {
                float a = As[ty * 4 + mi][kk];
                acc[mi].x += a * bv.x;
                acc[mi].y += a * bv.y;
                acc[mi].z += a * bv.z;
                acc[mi].w += a * bv.w;
            }
        }
    }

    float4 bia = *(const float4*)(bias + c0 + tx * 4);
    #pragma unroll
    for (int mi = 0; mi < 4; ++mi) {
        int n = m0 + ty * 4 + mi;
        float4 o;
        o.x = tanhf(acc[mi].x + bia.x);
        o.y = tanhf(acc[mi].y + bia.y);
        o.z = tanhf(acc[mi].z + bia.z);
        o.w = tanhf(acc[mi].w + bia.w);
        *(float4*)(out + (size_t)n * HH + c0 + tx * 4) = o;
    }
}

// ---------------------------------------------------------------------------
// K4: partial logits per g-group:
//   part[g,n,r] = sum_{i,j} h[n,g*64+i]*t[n,g*64+j]*Wc[(g*64+i)*64+j, r]
// A-panel (outer product) generated on the fly from LDS h/t tiles;
// Wc streamed from global (L2-resident: each block reads its 1.6MB g-slice).
// ---------------------------------------------------------------------------
__global__ __launch_bounds__(256) void k_logits_part(
        const float* __restrict__ h, const float* __restrict__ t,
        const float* __restrict__ Wc, float* __restrict__ part) {
    int n0 = blockIdx.x * 64;
    int g  = blockIdx.y;

    __shared__ float hsb[64][68];
    __shared__ float ts[64][68];

    int tid = threadIdx.x;
    #pragma unroll
    for (int it = 0; it < 4; ++it) {
        int q = (tid + it * 256) * 4;
        int ii = q & 63, nn = q >> 6;
        *(float4*)(&hsb[nn][ii]) = *(const float4*)(h + (size_t)(n0 + nn) * HH + g * 64 + ii);
        *(float4*)(&ts[nn][ii])  = *(const float4*)(t + (size_t)(n0 + nn) * HH + g * 64 + ii);
    }
    __syncthreads();

    int tx = tid & 15;   // r = tx + 16u
    int ty = tid >> 4;   // n-local = ty + 16v
    float acc[4][7] = {};

    for (int i = 0; i < 64; ++i) {
        float hv[4];
        #pragma unroll
        for (int v = 0; v < 4; ++v) hv[v] = hsb[ty + 16 * v][i];
        const float* wbase = Wc + (size_t)((g * 64 + i) * 64) * RR;
        for (int j = 0; j < 64; ++j) {
            float av[4];
            #pragma unroll
            for (int v = 0; v < 4; ++v) av[v] = hv[v] * ts[ty + 16 * v][j];
            const float* wrow = wbase + (size_t)j * RR;
            #pragma unroll
            for (int u = 0; u < 7; ++u) {
                int r = tx + 16 * u;
                if (r < RR) {
                    float wv = wrow[r];
                    #pragma unroll
                    for (int v = 0; v < 4; ++v) acc[v][u] += av[v] * wv;
                }
            }
        }
    }

    #pragma unroll
    for (int u = 0; u < 7; ++u) {
        int r = tx + 16 * u;
        if (r >= RR) continue;
        #pragma unroll
        for (int v = 0; v < 4; ++v) {
            int n = n0 + ty + 16 * v;
            part[((size_t)g * NN + n) * RR + r] = acc[v][u];
        }
    }
}

// ---------------------------------------------------------------------------
// K5: logits[n,r] = bc[r] + sum_g part[g,n,r]
// ---------------------------------------------------------------------------
__global__ __launch_bounds__(256) void k_reduce(
        const float* __restrict__ part, const float* __restrict__ bc,
        float* __restrict__ out) {
    int idx = blockIdx.x * 256 + threadIdx.x;
    if (idx >= NN * RR) return;
    int r = idx % RR;
    float s = bc[r];
    #pragma unroll
    for (int g = 0; g < GG; ++g) s += part[(size_t)g * NN * RR + idx];
    out[idx] = s;
}

// ---------------------------------------------------------------------------
extern "C" void kernel_launch(void* const* d_in, const int* in_sizes, int n_in,
                              void* d_out, int out_size, void* d_ws, size_t ws_size,
                              hipStream_t stream) {
    const float* hid  = (const float*)d_in[0];
    const float* att  = (const float*)d_in[1];
    const float* am   = (const float*)d_in[2];
    const int*   head = (const int*)d_in[3];
    const int*   tail = (const int*)d_in[4];
    const float* Wh   = (const float*)d_in[5];
    const float* bh   = (const float*)d_in[6];
    const float* Wt   = (const float*)d_in[7];
    const float* bt   = (const float*)d_in[8];
    const float* Wc   = (const float*)d_in[9];
    const float* bc   = (const float*)d_in[10];
    float* out = (float*)d_out;

    float* w = (float*)d_ws;
    float* ent_feat = w;  w += (size_t)BB * EE * HH;        //  98304
    float* ent_attn = w;  w += (size_t)BB * EE * LL;        // 131072
    float* inv_s    = w;  w += 4096;                        //   3968 used
    float* ht_info  = w;  w += (size_t)NN * HH;             // 3047424
    float* hbuf     = w;  w += (size_t)NN * HH;
    float* tbuf     = w;  w += (size_t)NN * HH;
    float* part     = w;  w += (size_t)GG * NN * RR;        // 4618752
    // total ~40 MB of f32 workspace

    k_ent_prep<<<BB * EE, 256, 0, stream>>>(hid, att, head, tail, ent_feat, ent_attn);
    k_pair_inv<<<BB * PP, 256, 0, stream>>>(ent_attn, am, inv_s);
    k_ht_info<<<dim3(HH / 128, PP / 32, BB), 256, 0, stream>>>(hid, ent_attn, am, inv_s, ht_info);
    k_proj<0><<<dim3(HH / 64, NN / 64), 256, 0, stream>>>(ent_feat, ht_info, Wh, bh, hbuf);
    k_proj<1><<<dim3(HH / 64, NN / 64), 256, 0, stream>>>(ent_feat, ht_info, Wt, bt, tbuf);
    k_logits_part<<<dim3(NN / 64, GG), 256, 0, stream>>>(hbuf, tbuf, Wc, part);
    k_reduce<<<(NN * RR + 255) / 256, 256, 0, stream>>>(part, bc, out);
}

// Round 2
// 567.448 us; speedup vs baseline: 2.9474x; 2.9474x over previous
//
#include <hip/hip_runtime.h>
#include <hip/hip_bf16.h>
#include <cstdint>
#include <cstddef>

#define BB 4
#define LL 1024
#define HH 768
#define AA 12
#define EE 32
#define PP 992          // EE*(EE-1)
#define NN (BB*PP)      // 3968
#define RR 97
#define GG 12           // HH/64
#define RP 112          // R padded to 7 tiles of 16
#define KG 4096         // K per g-group (64*64)
#define KS 128          // K-steps of 32 per g-group

using floatx4 = __attribute__((ext_vector_type(4))) float;
using shortx8 = __attribute__((ext_vector_type(8))) short;

__device__ __forceinline__ short bf16r(float x) {
    __hip_bfloat16 b = __float2bfloat16(x);
    return *(short*)&b;
}

__device__ __forceinline__ void pair_decode(int p, int& i0, int& i1) {
    i0 = p / 31;
    int r = p - i0 * 31;
    i1 = r + (r >= i0 ? 1 : 0);
}

// ---------------------------------------------------------------------------
// K0: per (b,e): ent_feat = 0.5*(hid[hd]+hid[tl]);
//     ent_attn = (0.5/A) * sum_a (att[a,hd,:]+att[a,tl,:])
// Only gathers the <=64 attention rows actually used (12.6 MB, not 192 MB).
// ---------------------------------------------------------------------------
__global__ __launch_bounds__(256) void k_ent_prep(
        const float* __restrict__ hid, const float* __restrict__ att,
        const int* __restrict__ head, const int* __restrict__ tail,
        float* __restrict__ ent_feat, float* __restrict__ ent_attn) {
    int be = blockIdx.x;
    int b  = be >> 5;
    int hd = head[be];
    int tl = tail[be];

    const float* hrow = hid + ((size_t)b * LL + hd) * HH;
    const float* trow = hid + ((size_t)b * LL + tl) * HH;
    for (int hh = threadIdx.x; hh < HH; hh += 256)
        ent_feat[(size_t)be * HH + hh] = 0.5f * (hrow[hh] + trow[hh]);

    const float* abase = att + (size_t)b * AA * LL * LL;
    for (int l = threadIdx.x; l < LL; l += 256) {
        float s = 0.f;
        #pragma unroll
        for (int a = 0; a < AA; ++a) {
            const float* ar = abase + (size_t)a * LL * LL;
            s += ar[(size_t)hd * LL + l] + ar[(size_t)tl * LL + l];
        }
        ent_attn[(size_t)be * LL + l] = s * (0.5f / AA);
    }
}

// ---------------------------------------------------------------------------
// K1: inv_s[b,p] = 1 / (sum_l e0*e1*am + 1e-20)
// ---------------------------------------------------------------------------
__global__ __launch_bounds__(256) void k_pair_inv(
        const float* __restrict__ ent_attn, const float* __restrict__ am,
        float* __restrict__ inv_s) {
    int bp = blockIdx.x;
    int b = bp / PP, p = bp - b * PP;
    int i0, i1; pair_decode(p, i0, i1);
    const float* e0  = ent_attn + ((size_t)b * EE + i0) * LL;
    const float* e1  = ent_attn + ((size_t)b * EE + i1) * LL;
    const float* amr = am + (size_t)b * LL;
    float s = 0.f;
    for (int l = threadIdx.x; l < LL; l += 256)
        s += e0[l] * e1[l] * amr[l];
    #pragma unroll
    for (int off = 32; off > 0; off >>= 1) s += __shfl_down(s, off, 64);
    __shared__ float red[4];
    int lane = threadIdx.x & 63, w = threadIdx.x >> 6;
    if (lane == 0) red[w] = s;
    __syncthreads();
    if (threadIdx.x == 0) {
        float tt = red[0] + red[1] + red[2] + red[3];
        inv_s[bp] = 1.0f / (tt + 1e-20f);
    }
}

// ---------------------------------------------------------------------------
// K2: ht_info[b,p,:] = inv_s * sum_l (e0*e1*am) * hid[b,l,:]
// ---------------------------------------------------------------------------
__global__ __launch_bounds__(256) void k_ht_info(
        const float* __restrict__ hid, const float* __restrict__ ent_attn,
        const float* __restrict__ am, const float* __restrict__ inv_s,
        float* __restrict__ ht_info) {
    int b  = blockIdx.z;
    int p0 = blockIdx.y * 32;
    int c0 = blockIdx.x * 128;

    __shared__ float ea[EE][36];
    __shared__ float ams[32];
    __shared__ float hs[32][132];

    int tid = threadIdx.x;
    int px = tid >> 5;
    int cx = tid & 31;

    int i0[4], i1[4]; float inv[4];
    #pragma unroll
    for (int pp = 0; pp < 4; ++pp) {
        int p = p0 + px * 4 + pp;
        pair_decode(p, i0[pp], i1[pp]);
        inv[pp] = inv_s[b * PP + p];
    }

    float4 acc[4] = {};

    for (int l0 = 0; l0 < LL; l0 += 32) {
        __syncthreads();
        {
            int q = tid * 4;
            int ll = q & 31, ee = q >> 5;
            float4 v = *(const float4*)(ent_attn + ((size_t)b * EE + ee) * LL + l0 + ll);
            *(float4*)(&ea[ee][ll]) = v;
        }
        if (tid < 32) ams[tid] = am[(size_t)b * LL + l0 + tid];
        #pragma unroll
        for (int it = 0; it < 4; ++it) {
            int q = (tid + it * 256) * 4;
            int cc = q & 127, ll = q >> 7;
            float4 v = *(const float4*)(hid + ((size_t)b * LL + l0 + ll) * HH + c0 + cc);
            *(float4*)(&hs[ll][cc]) = v;
        }
        __syncthreads();
        #pragma unroll
        for (int l = 0; l < 32; ++l) {
            float amv = ams[l];
            float4 hv = *(const float4*)(&hs[l][cx * 4]);
            #pragma unroll
            for (int pp = 0; pp < 4; ++pp) {
                float wgt = ea[i0[pp]][l] * ea[i1[pp]][l] * amv;
                acc[pp].x += wgt * hv.x;
                acc[pp].y += wgt * hv.y;
                acc[pp].z += wgt * hv.z;
                acc[pp].w += wgt * hv.w;
            }
        }
    }

    #pragma unroll
    for (int pp = 0; pp < 4; ++pp) {
        int p = p0 + px * 4 + pp;
        float4 o;
        o.x = acc[pp].x * inv[pp];
        o.y = acc[pp].y * inv[pp];
        o.z = acc[pp].z * inv[pp];
        o.w = acc[pp].w * inv[pp];
        *(float4*)(ht_info + ((size_t)(b * PP + p)) * HH + c0 + cx * 4) = o;
    }
}

// ---------------------------------------------------------------------------
// K3: out[n,:] = tanh(concat(ent_feat[ent(n)], ht_info[n]) @ W + bias)  (f32)
// ---------------------------------------------------------------------------
template <int WHICH>
__global__ __launch_bounds__(256) void k_proj(
        const float* __restrict__ ent_feat, const float* __restrict__ ht_info,
        const float* __restrict__ W, const float* __restrict__ bias,
        float* __restrict__ out) {
    int m0 = blockIdx.y * 64;
    int c0 = blockIdx.x * 64;

    __shared__ float As[64][20];
    __shared__ float Bs[16][68];

    int tid = threadIdx.x;
    int tx = tid & 15;
    int ty = tid >> 4;

    int qa = tid * 4;
    int akk = qa & 15, amm = qa >> 4;
    int qb = tid * 4;
    int bcc = qb & 63, bkk = qb >> 6;

    int n_a = m0 + amm;
    int b_a = n_a / PP, p_a = n_a - b_a * PP;
    int ia0, ia1; pair_decode(p_a, ia0, ia1);
    int ent = (WHICH == 0) ? ia0 : ia1;
    const float* featrow = ent_feat + ((size_t)(b_a * EE + ent)) * HH;
    const float* htrow   = ht_info + ((size_t)(b_a * PP + p_a)) * HH;

    float4 acc[4] = {};

    for (int k0 = 0; k0 < 2 * HH; k0 += 16) {
        __syncthreads();
        {
            const float* src = (k0 < HH) ? (featrow + k0 + akk)
                                         : (htrow + (k0 - HH) + akk);
            float4 v = *(const float4*)src;
            *(float4*)(&As[amm][akk]) = v;
        }
        {
            float4 v = *(const float4*)(W + (size_t)(k0 + bkk) * HH + c0 + bcc);
            *(float4*)(&Bs[bkk][bcc]) = v;
        }
        __syncthreads();
        #pragma unroll
        for (int kk = 0; kk < 16; ++kk) {
            float4 bv = *(const float4*)(&Bs[kk][tx * 4]);
            #pragma unroll
            for (int mi = 0; mi < 4; ++mi) {
                float a = As[ty * 4 + mi][kk];
                acc[mi].x += a * bv.x;
                acc[mi].y += a * bv.y;
                acc[mi].z += a * bv.z;
                acc[mi].w += a * bv.w;
            }
        }
    }

    float4 bia = *(const float4*)(bias + c0 + tx * 4);
    #pragma unroll
    for (int mi = 0; mi < 4; ++mi) {
        int n = m0 + ty * 4 + mi;
        float4 o;
        o.x = tanhf(acc[mi].x + bia.x);
        o.y = tanhf(acc[mi].y + bia.y);
        o.z = tanhf(acc[mi].z + bia.z);
        o.w = tanhf(acc[mi].w + bia.w);
        *(float4*)(out + (size_t)n * HH + c0 + tx * 4) = o;
    }
}

// ---------------------------------------------------------------------------
// K4a: pack Wc (f32 [K=49152][97]) into bf16 MFMA B-fragments, padded R->112.
// Layout: Wcp[((g*128 + kstep)*7 + rt)*64 + lane][8 bf16]
//   fragment element e maps to B[k = g*4096 + kstep*32 + (lane>>4)*8 + e]
//                          [r = rt*16 + (lane&15)]
// ---------------------------------------------------------------------------
__global__ __launch_bounds__(256) void k_pack_wc(
        const float* __restrict__ Wc, short* __restrict__ Wcp) {
    int idx = blockIdx.x * 256 + threadIdx.x;   // 12*128*7*64 = 688128 total
    int lane = idx & 63;
    int fr   = idx >> 6;
    int rt = fr % 7;
    int ks = (fr / 7) % KS;
    int g  = fr / (7 * KS);
    int r  = rt * 16 + (lane & 15);
    int kb = g * KG + ks * 32 + (lane >> 4) * 8;
    short v[8];
    #pragma unroll
    for (int e = 0; e < 8; ++e) {
        float x = (r < RR) ? Wc[(size_t)(kb + e) * RR + r] : 0.f;
        v[e] = bf16r(x);
    }
    *(shortx8*)(Wcp + (size_t)idx * 8) = *(const shortx8*)v;
}

// ---------------------------------------------------------------------------
// K4b: MFMA logits partials per g:
//   part[g,n,r] = sum_{i,j} h[n,g64+i]*t[n,g64+j]*Wc[(g64+i)*64+j, r]
// A[n,k]=h[n,gi]*t[n,gj] generated in-register from f32 LDS tiles;
// B fragments streamed from pre-packed Wcp (L1/L2-hit). No barrier in K-loop.
// Wave w computes rows n0+16w..+15 x all 112 (padded) r-cols.
// ---------------------------------------------------------------------------
__global__ __launch_bounds__(256) void k_logits_mfma(
        const float* __restrict__ h, const float* __restrict__ t,
        const short* __restrict__ Wcp, float* __restrict__ part) {
    int n0 = blockIdx.x * 64;
    int g  = blockIdx.y;

    __shared__ float ht_[64][66];   // stride 66 w -> banks 2n%32, conflict-free
    __shared__ float tt_[64][76];   // stride 76 w -> 2-way on b128 (free)

    int tid = threadIdx.x;
    #pragma unroll
    for (int it = 0; it < 4; ++it) {
        int idx = tid + it * 256;
        int row = idx >> 4;
        int c4  = (idx & 15) * 4;
        float4 hv = *(const float4*)(h + (size_t)(n0 + row) * HH + g * 64 + c4);
        float4 tv = *(const float4*)(t + (size_t)(n0 + row) * HH + g * 64 + c4);
        *(float4*)(&ht_[row][c4]) = hv;
        *(float4*)(&tt_[row][c4]) = tv;
    }
    __syncthreads();

    int lane = tid & 63, wave = tid >> 6;
    int nloc = wave * 16 + (lane & 15);
    int kgrp = lane >> 4;

    floatx4 acc[7] = {};
    const shortx8* wbase = (const shortx8*)Wcp + (size_t)g * KS * 7 * 64 + lane;

    #pragma unroll 2
    for (int kstep = 0; kstep < KS; ++kstep) {
        int i  = kstep >> 1;
        int j0 = (kstep & 1) * 32;
        float hv = ht_[nloc][i];
        const float* tp = &tt_[nloc][j0 + kgrp * 8];
        float4 t0 = *(const float4*)tp;
        float4 t1 = *(const float4*)(tp + 4);
        shortx8 av;
        av[0] = bf16r(hv * t0.x); av[1] = bf16r(hv * t0.y);
        av[2] = bf16r(hv * t0.z); av[3] = bf16r(hv * t0.w);
        av[4] = bf16r(hv * t1.x); av[5] = bf16r(hv * t1.y);
        av[6] = bf16r(hv * t1.z); av[7] = bf16r(hv * t1.w);
        const shortx8* wk = wbase + (size_t)kstep * 7 * 64;
        #pragma unroll
        for (int rt = 0; rt < 7; ++rt) {
            shortx8 bv = wk[(size_t)rt * 64];
            acc[rt] = __builtin_amdgcn_mfma_f32_16x16x32_bf16(av, bv, acc[rt], 0, 0, 0);
        }
    }

    // C/D layout (verified m89): col = lane&15, row = (lane>>4)*4 + reg
    int rb = lane & 15;
    int nb = n0 + wave * 16 + (lane >> 4) * 4;
    #pragma unroll
    for (int rt = 0; rt < 7; ++rt)
        #pragma unroll
        for (int q = 0; q < 4; ++q)
            part[((size_t)g * NN + nb + q) * RP + rt * 16 + rb] = acc[rt][q];
}

// ---------------------------------------------------------------------------
// K5: logits[n,r] = bc[r] + sum_g part[g,n,r]
// ---------------------------------------------------------------------------
__global__ __launch_bounds__(256) void k_reduce(
        const float* __restrict__ part, const float* __restrict__ bc,
        float* __restrict__ out) {
    int idx = blockIdx.x * 256 + threadIdx.x;
    if (idx >= NN * RR) return;
    int n = idx / RR;
    int r = idx - n * RR;
    float s = bc[r];
    #pragma unroll
    for (int g = 0; g < GG; ++g) s += part[((size_t)g * NN + n) * RP + r];
    out[idx] = s;
}

// ---------------------------------------------------------------------------
extern "C" void kernel_launch(void* const* d_in, const int* in_sizes, int n_in,
                              void* d_out, int out_size, void* d_ws, size_t ws_size,
                              hipStream_t stream) {
    const float* hid  = (const float*)d_in[0];
    const float* att  = (const float*)d_in[1];
    const float* am   = (const float*)d_in[2];
    const int*   head = (const int*)d_in[3];
    const int*   tail = (const int*)d_in[4];
    const float* Wh   = (const float*)d_in[5];
    const float* bh   = (const float*)d_in[6];
    const float* Wt   = (const float*)d_in[7];
    const float* bt   = (const float*)d_in[8];
    const float* Wc   = (const float*)d_in[9];
    const float* bc   = (const float*)d_in[10];
    float* out = (float*)d_out;

    float* w = (float*)d_ws;
    float* ent_feat = w;  w += (size_t)BB * EE * HH;        //    98304
    float* ent_attn = w;  w += (size_t)BB * EE * LL;        //   131072
    float* inv_s    = w;  w += 4096;
    float* ht_info  = w;  w += (size_t)NN * HH;             //  3047424
    float* hbuf     = w;  w += (size_t)NN * HH;
    float* tbuf     = w;  w += (size_t)NN * HH;
    float* part     = w;  w += (size_t)GG * NN * RP;        //  5332992
    short* Wcp      = (short*)w;                            // 11.0 MB bf16
    // total ~70 MB

    k_pack_wc<<<(GG * KS * 7 * 64) / 256, 256, 0, stream>>>(Wc, Wcp);
    k_ent_prep<<<BB * EE, 256, 0, stream>>>(hid, att, head, tail, ent_feat, ent_attn);
    k_pair_inv<<<BB * PP, 256, 0, stream>>>(ent_attn, am, inv_s);
    k_ht_info<<<dim3(HH / 128, PP / 32, BB), 256, 0, stream>>>(hid, ent_attn, am, inv_s, ht_info);
    k_proj<0><<<dim3(HH / 64, NN / 64), 256, 0, stream>>>(ent_feat, ht_info, Wh, bh, hbuf);
    k_proj<1><<<dim3(HH / 64, NN / 64), 256, 0, stream>>>(ent_feat, ht_info, Wt, bt, tbuf);
    k_logits_mfma<<<dim3(NN / 64, GG), 256, 0, stream>>>(hbuf, tbuf, Wcp, part);
    k_reduce<<<(NN * RR + 255) / 256, 256, 0, stream>>>(part, bc, out);
}

// Round 3
// 286.985 us; speedup vs baseline: 5.8279x; 1.9773x over previous
//
#include <hip/hip_runtime.h>
#include <cstdint>
#include <cstddef>

#define BB 4
#define LL 1024
#define HH 768
#define AA 12
#define EE 32
#define PP 992           // EE*(EE-1)
#define PPAD 1024        // padded pairs per batch
#define NROW (BB*PPAD)   // 4096
#define NN (BB*PP)       // 3968
#define RR 97
#define RP 112           // R padded to 7 tiles of 16
#define GG 12

typedef __attribute__((ext_vector_type(8))) _Float16 half8;
typedef __attribute__((ext_vector_type(4))) _Float16 half4;
typedef __attribute__((ext_vector_type(4))) float floatx4;

__device__ __forceinline__ void pair_decode(int p, int& i0, int& i1) {
    i0 = p / 31;
    int r = p - i0 * 31;
    i1 = r + (r >= i0 ? 1 : 0);
}

// ---------------------------------------------------------------------------
// Generic fragment packer: src f32 [K][NC] row-major -> f16 MFMA B-fragments.
// dst[((ks*CT + ct)*64 + lane)*8 + e] = src[ks*32 + (lane>>4)*8 + e][ct*16 + (lane&15)]
// (zero-padded for c >= NC)
// ---------------------------------------------------------------------------
__global__ __launch_bounds__(256) void k_pack_frag(
        const float* __restrict__ src, _Float16* __restrict__ dst,
        int K32, int CT, int NC) {
    int idx = blockIdx.x * 256 + threadIdx.x;
    int lane = idx & 63;
    int f = idx >> 6;
    int ct = f % CT;
    int ks = f / CT;
    if (ks >= K32) return;
    int c  = ct * 16 + (lane & 15);
    int kb = ks * 32 + (lane >> 4) * 8;
    _Float16 v[8];
    #pragma unroll
    for (int e = 0; e < 8; ++e)
        v[e] = (c < NC) ? (_Float16)src[(size_t)(kb + e) * NC + c] : (_Float16)0.f;
    *(half8*)(dst + (size_t)idx * 8) = *(const half8*)v;
}

// ---------------------------------------------------------------------------
// hid f32 -> f16 row-major
// ---------------------------------------------------------------------------
__global__ __launch_bounds__(256) void k_pack_hid(
        const float* __restrict__ hid, _Float16* __restrict__ hidb) {
    int idx = blockIdx.x * 256 + threadIdx.x;
    const float* s = hid + (size_t)idx * 8;
    float4 a = *(const float4*)s;
    float4 b = *(const float4*)(s + 4);
    half8 v = { (_Float16)a.x, (_Float16)a.y, (_Float16)a.z, (_Float16)a.w,
                (_Float16)b.x, (_Float16)b.y, (_Float16)b.z, (_Float16)b.w };
    *(half8*)(hidb + (size_t)idx * 8) = v;
}

// ---------------------------------------------------------------------------
// K0: ent_feat = 0.5*(hid[hd]+hid[tl]); ent_attn = (0.5/A)*sum_a(att rows)
// Gathers only the <=64 attention rows used (12.6 MB, not 192 MB).
// ---------------------------------------------------------------------------
__global__ __launch_bounds__(256) void k_ent_prep(
        const float* __restrict__ hid, const float* __restrict__ att,
        const int* __restrict__ head, const int* __restrict__ tail,
        float* __restrict__ ent_feat, float* __restrict__ ent_attn) {
    int be = blockIdx.x;
    int b  = be >> 5;
    int hd = head[be];
    int tl = tail[be];

    const float* hrow = hid + ((size_t)b * LL + hd) * HH;
    const float* trow = hid + ((size_t)b * LL + tl) * HH;
    for (int hh = threadIdx.x; hh < HH; hh += 256)
        ent_feat[(size_t)be * HH + hh] = 0.5f * (hrow[hh] + trow[hh]);

    const float* abase = att + (size_t)b * AA * LL * LL;
    for (int l = threadIdx.x; l < LL; l += 256) {
        float s = 0.f;
        #pragma unroll
        for (int a = 0; a < AA; ++a) {
            const float* ar = abase + (size_t)a * LL * LL;
            s += ar[(size_t)hd * LL + l] + ar[(size_t)tl * LL + l];
        }
        ent_attn[(size_t)be * LL + l] = s * (0.5f / AA);
    }
}

// ---------------------------------------------------------------------------
// K1: pairw[b,p,l] = f16( e0*e1*am / (sum + 1e-20) ); padded rows zeroed.
// ---------------------------------------------------------------------------
__global__ __launch_bounds__(256) void k_pairw(
        const float* __restrict__ ent_attn, const float* __restrict__ am,
        _Float16* __restrict__ pairw) {
    int prow = blockIdx.x;             // b*1024 + p
    int b = prow >> 10, p = prow & 1023;
    int tid = threadIdx.x;
    _Float16* dst = pairw + (size_t)prow * LL;
    if (p >= PP) {
        half4 z = {};
        *(half4*)(dst + tid * 4) = z;
        return;
    }
    int i0, i1; pair_decode(p, i0, i1);
    const float* e0  = ent_attn + ((size_t)b * EE + i0) * LL;
    const float* e1  = ent_attn + ((size_t)b * EE + i1) * LL;
    const float* amr = am + (size_t)b * LL;
    float4 a = *(const float4*)(e0 + tid * 4);
    float4 c = *(const float4*)(e1 + tid * 4);
    float4 m = *(const float4*)(amr + tid * 4);
    float w0 = a.x * c.x * m.x, w1 = a.y * c.y * m.y;
    float w2 = a.z * c.z * m.z, w3 = a.w * c.w * m.w;
    float s = w0 + w1 + w2 + w3;
    #pragma unroll
    for (int off = 32; off > 0; off >>= 1) s += __shfl_down(s, off, 64);
    __shared__ float red[4];
    __shared__ float sinv;
    int lane = tid & 63, wv = tid >> 6;
    if (lane == 0) red[wv] = s;
    __syncthreads();
    if (tid == 0) sinv = 1.0f / (red[0] + red[1] + red[2] + red[3] + 1e-20f);
    __syncthreads();
    float inv = sinv;
    half4 o = { (_Float16)(w0 * inv), (_Float16)(w1 * inv),
                (_Float16)(w2 * inv), (_Float16)(w3 * inv) };
    *(half4*)(dst + tid * 4) = o;
}

// ---------------------------------------------------------------------------
// K2: Fht[mat,b,e,:] = ent_feat[b,e]@W1 + bias   (f32, tiny: 128x768x768 x2)
// ---------------------------------------------------------------------------
__global__ __launch_bounds__(256) void k_fht(
        const float* __restrict__ ent_feat,
        const float* __restrict__ Wh, const float* __restrict__ bh,
        const float* __restrict__ Wt, const float* __restrict__ bt,
        float* __restrict__ Fht) {
    int ct  = blockIdx.x;   // 12 col-tiles of 64
    int b   = blockIdx.y;
    int mat = blockIdx.z;
    const float* W    = mat ? Wt : Wh;   // first 768 rows = W1 half
    const float* bias = mat ? bt : bh;

    __shared__ float fs[EE][68];
    __shared__ float ws_[64][68];
    int tid = threadIdx.x;
    int e = tid >> 3, cg = tid & 7;
    float acc[8] = {};
    for (int k0 = 0; k0 < HH; k0 += 64) {
        __syncthreads();
        #pragma unroll
        for (int it = 0; it < 2; ++it) {
            int idx = tid + it * 256;
            int ee = idx >> 4, kk = (idx & 15) * 4;
            *(float4*)(&fs[ee][kk]) =
                *(const float4*)(ent_feat + ((size_t)b * EE + ee) * HH + k0 + kk);
        }
        #pragma unroll
        for (int it = 0; it < 4; ++it) {
            int idx = tid + it * 256;
            int kk = idx >> 4, cc = (idx & 15) * 4;
            *(float4*)(&ws_[kk][cc]) =
                *(const float4*)(W + (size_t)(k0 + kk) * HH + ct * 64 + cc);
        }
        __syncthreads();
        #pragma unroll
        for (int kk = 0; kk < 64; ++kk) {
            float f = fs[e][kk];
            float4 w0 = *(const float4*)(&ws_[kk][cg * 8]);
            float4 w1 = *(const float4*)(&ws_[kk][cg * 8 + 4]);
            acc[0] += f * w0.x; acc[1] += f * w0.y; acc[2] += f * w0.z; acc[3] += f * w0.w;
            acc[4] += f * w1.x; acc[5] += f * w1.y; acc[6] += f * w1.z; acc[7] += f * w1.w;
        }
    }
    int cbase = ct * 64 + cg * 8;
    float* dst = Fht + (((size_t)mat * BB + b) * EE + e) * HH + cbase;
    #pragma unroll
    for (int j = 0; j < 8; ++j) dst[j] = acc[j] + bias[cbase + j];
}

// ---------------------------------------------------------------------------
// K3: Vh = hidb@Wh2, Vt = hidb@Wt2 (shared A), output scattered directly
// into proj-B fragment layout. M=4096, K=768, N=768.
// ---------------------------------------------------------------------------
__global__ __launch_bounds__(256) void k_vgemm(
        const _Float16* __restrict__ hidb,
        const _Float16* __restrict__ Whf, const _Float16* __restrict__ Wtf,
        _Float16* __restrict__ Vhf, _Float16* __restrict__ Vtf) {
    int tid = threadIdx.x;
    int lane = tid & 63, wv = tid >> 6;
    int M0  = blockIdx.x * 64 + wv * 16;
    int ct0 = blockIdx.y * 4;

    const _Float16* arow = hidb + (size_t)(M0 + (lane & 15)) * HH + (lane >> 4) * 8;
    const half8* bh8 = (const half8*)Whf + lane;
    const half8* bt8 = (const half8*)Wtf + lane;

    floatx4 ah[4] = {}, at[4] = {};
    #pragma unroll 4
    for (int ks = 0; ks < HH / 32; ++ks) {
        half8 av = *(const half8*)(arow + ks * 32);
        #pragma unroll
        for (int ct = 0; ct < 4; ++ct) {
            size_t fo = (size_t)(ks * 48 + ct0 + ct) * 64;
            ah[ct] = __builtin_amdgcn_mfma_f32_16x16x32_f16(av, bh8[fo], ah[ct], 0, 0, 0);
            at[ct] = __builtin_amdgcn_mfma_f32_16x16x32_f16(av, bt8[fo], at[ct], 0, 0, 0);
        }
    }
    // scatter C into proj-B fragment layout: k = row m, c = col
    int b = M0 >> 10, mloc = M0 & 1023;
    int ksp = mloc >> 5;
    int u = lane >> 4;
    int laneL = (((mloc >> 3) & 3) + (u >> 1)) * 16 + (lane & 15);
    int estart = (u & 1) * 4;
    size_t bofs = (size_t)b * (32 * 48 * 64 * 8);
    #pragma unroll
    for (int ct = 0; ct < 4; ++ct) {
        size_t base = bofs + ((size_t)(ksp * 48 + ct0 + ct) * 64 + laneL) * 8 + estart;
        half4 hv = { (_Float16)ah[ct][0], (_Float16)ah[ct][1],
                     (_Float16)ah[ct][2], (_Float16)ah[ct][3] };
        half4 tv = { (_Float16)at[ct][0], (_Float16)at[ct][1],
                     (_Float16)at[ct][2], (_Float16)at[ct][3] };
        *(half4*)(Vhf + base) = hv;
        *(half4*)(Vtf + base) = tv;
    }
}

// ---------------------------------------------------------------------------
// K4: h = tanh(Fh[i0] + pairw@Vh), t = tanh(Ft[i1] + pairw@Vt)  (fused)
// M=1024/batch (padded), K=1024, N=768. Outputs f16 row-major.
// ---------------------------------------------------------------------------
__global__ __launch_bounds__(256) void k_proj_mfma(
        const _Float16* __restrict__ pairw,
        const _Float16* __restrict__ Vhf, const _Float16* __restrict__ Vtf,
        const float* __restrict__ Fht,
        _Float16* __restrict__ hb, _Float16* __restrict__ tb) {
    int tid = threadIdx.x;
    int lane = tid & 63, wv = tid >> 6;
    int b   = blockIdx.z;
    int M0  = blockIdx.x * 64 + wv * 16;   // row within batch
    int ct0 = blockIdx.y * 4;

    const _Float16* arow =
        pairw + ((size_t)b * PPAD + M0 + (lane & 15)) * LL + (lane >> 4) * 8;
    const half8* vh8 = (const half8*)(Vhf + (size_t)b * (32 * 48 * 64 * 8)) + lane;
    const half8* vt8 = (const half8*)(Vtf + (size_t)b * (32 * 48 * 64 * 8)) + lane;

    floatx4 ah[4] = {}, at4[4] = {};
    #pragma unroll 4
    for (int ks = 0; ks < LL / 32; ++ks) {
        half8 av = *(const half8*)(arow + ks * 32);
        #pragma unroll
        for (int ct = 0; ct < 4; ++ct) {
            size_t fo = (size_t)(ks * 48 + ct0 + ct) * 64;
            ah[ct]  = __builtin_amdgcn_mfma_f32_16x16x32_f16(av, vh8[fo], ah[ct], 0, 0, 0);
            at4[ct] = __builtin_amdgcn_mfma_f32_16x16x32_f16(av, vt8[fo], at4[ct], 0, 0, 0);
        }
    }
    int u = lane >> 4;
    int i0q[4], i1q[4];
    #pragma unroll
    for (int q = 0; q < 4; ++q) {
        int p = M0 + u * 4 + q;
        if (p < PP) pair_decode(p, i0q[q], i1q[q]);
        else { i0q[q] = 0; i1q[q] = 0; }
    }
    const float* FhB = Fht + (size_t)b * EE * HH;
    const float* FtB = Fht + ((size_t)(BB + b)) * EE * HH;
    #pragma unroll
    for (int ct = 0; ct < 4; ++ct) {
        int c = (ct0 + ct) * 16 + (lane & 15);
        #pragma unroll
        for (int q = 0; q < 4; ++q) {
            int p = M0 + u * 4 + q;
            size_t row = (size_t)b * PPAD + p;
            float hv = tanhf(ah[ct][q]  + FhB[(size_t)i0q[q] * HH + c]);
            float tv = tanhf(at4[ct][q] + FtB[(size_t)i1q[q] * HH + c]);
            hb[row * HH + c] = (_Float16)hv;
            tb[row * HH + c] = (_Float16)tv;
        }
    }
}

// ---------------------------------------------------------------------------
// K5: MFMA logits partials per g (f16 part):
//   part[g,n,r] = sum_{i,j} h[n,g64+i]*t[n,g64+j]*Wc[(g64+i)*64+j, r]
// A generated in-register from f32 LDS tiles; B from pre-packed Wcp.
// ---------------------------------------------------------------------------
__global__ __launch_bounds__(256) void k_logits_mfma(
        const _Float16* __restrict__ hb, const _Float16* __restrict__ tb,
        const _Float16* __restrict__ Wcp, _Float16* __restrict__ part) {
    int n0 = blockIdx.x * 64;
    int g  = blockIdx.y;

    __shared__ float ht_[64][66];
    __shared__ float tt_[64][76];

    int tid = threadIdx.x;
    #pragma unroll
    for (int it = 0; it < 2; ++it) {
        int idx = tid + it * 256;
        int row = idx >> 3;
        int c8  = (idx & 7) * 8;
        half8 hv8 = *(const half8*)(hb + (size_t)(n0 + row) * HH + g * 64 + c8);
        half8 tv8 = *(const half8*)(tb + (size_t)(n0 + row) * HH + g * 64 + c8);
        #pragma unroll
        for (int j = 0; j < 8; ++j) {
            ht_[row][c8 + j] = (float)hv8[j];
            tt_[row][c8 + j] = (float)tv8[j];
        }
    }
    __syncthreads();

    int lane = tid & 63, wave = tid >> 6;
    int nloc = wave * 16 + (lane & 15);
    int kgrp = lane >> 4;

    floatx4 acc[7] = {};
    const half8* wbase = (const half8*)Wcp + (size_t)g * 128 * 7 * 64 + lane;

    #pragma unroll 2
    for (int kstep = 0; kstep < 128; ++kstep) {
        int i  = kstep >> 1;
        int j0 = (kstep & 1) * 32;
        float hv = ht_[nloc][i];
        const float* tp = &tt_[nloc][j0 + kgrp * 8];
        float4 t0 = *(const float4*)tp;
        float4 t1 = *(const float4*)(tp + 4);
        half8 av;
        av[0] = (_Float16)(hv * t0.x); av[1] = (_Float16)(hv * t0.y);
        av[2] = (_Float16)(hv * t0.z); av[3] = (_Float16)(hv * t0.w);
        av[4] = (_Float16)(hv * t1.x); av[5] = (_Float16)(hv * t1.y);
        av[6] = (_Float16)(hv * t1.z); av[7] = (_Float16)(hv * t1.w);
        const half8* wk = wbase + (size_t)kstep * 7 * 64;
        #pragma unroll
        for (int rt = 0; rt < 7; ++rt) {
            half8 bv = wk[(size_t)rt * 64];
            acc[rt] = __builtin_amdgcn_mfma_f32_16x16x32_f16(av, bv, acc[rt], 0, 0, 0);
        }
    }

    int rb = lane & 15;
    int nb = n0 + wave * 16 + (lane >> 4) * 4;
    #pragma unroll
    for (int rt = 0; rt < 7; ++rt)
        #pragma unroll
        for (int q = 0; q < 4; ++q)
            part[((size_t)g * NROW + nb + q) * RP + rt * 16 + rb] =
                (_Float16)acc[rt][q];
}

// ---------------------------------------------------------------------------
// K6: logits[n,r] = bc[r] + sum_g part[g, rowp(n), r]
// ---------------------------------------------------------------------------
__global__ __launch_bounds__(256) void k_reduce(
        const _Float16* __restrict__ part, const float* __restrict__ bc,
        float* __restrict__ out) {
    int idx = blockIdx.x * 256 + threadIdx.x;
    if (idx >= NN * RR) return;
    int n = idx / RR;
    int r = idx - n * RR;
    int b = n / PP, p = n - b * PP;
    size_t rowp = (size_t)b * PPAD + p;
    float s = bc[r];
    #pragma unroll
    for (int g = 0; g < GG; ++g)
        s += (float)part[((size_t)g * NROW + rowp) * RP + r];
    out[idx] = s;
}

// ---------------------------------------------------------------------------
extern "C" void kernel_launch(void* const* d_in, const int* in_sizes, int n_in,
                              void* d_out, int out_size, void* d_ws, size_t ws_size,
                              hipStream_t stream) {
    const float* hid  = (const float*)d_in[0];
    const float* att  = (const float*)d_in[1];
    const float* am   = (const float*)d_in[2];
    const int*   head = (const int*)d_in[3];
    const int*   tail = (const int*)d_in[4];
    const float* Wh   = (const float*)d_in[5];
    const float* bh   = (const float*)d_in[6];
    const float* Wt   = (const float*)d_in[7];
    const float* bt   = (const float*)d_in[8];
    const float* Wc   = (const float*)d_in[9];
    const float* bc   = (const float*)d_in[10];
    float* out = (float*)d_out;

    // ---- workspace layout (55 MB; 'part' aliases buffers dead before K5) ----
    char* w = (char*)d_ws;
    _Float16* Wcp = (_Float16*)w;  w += (size_t)1536 * 7 * 64 * 8 * 2;       // 11.01 MB
    _Float16* Vhf = (_Float16*)w;  w += (size_t)BB * 32 * 48 * 64 * 8 * 2;   //  6.29 MB
    _Float16* Vtf = (_Float16*)w;  w += (size_t)BB * 32 * 48 * 64 * 8 * 2;
    _Float16* hb  = (_Float16*)w;  w += (size_t)NROW * HH * 2;               //  6.29 MB
    _Float16* tb  = (_Float16*)w;  w += (size_t)NROW * HH * 2;
    float* Fht      = (float*)w;   w += (size_t)2 * BB * EE * HH * 4;        //  0.79 MB
    float* ent_feat = (float*)w;   w += (size_t)BB * EE * HH * 4;
    float* ent_attn = (float*)w;   w += (size_t)BB * EE * LL * 4;
    char* aliasb = w;
    _Float16* hidb  = (_Float16*)aliasb;                                     //  6.29 MB
    _Float16* Whf   = (_Float16*)(aliasb + (size_t)6291456);                 //  1.18 MB
    _Float16* Wtf   = (_Float16*)(aliasb + (size_t)6291456 + 1179648);
    _Float16* pairw = (_Float16*)(aliasb + (size_t)6291456 + 2 * 1179648);   //  8.39 MB
    // part (11.01 MB f16) overlaps hidb/Whf/Wtf/start-of-pairw: all of those
    // are last READ by k_vgemm/k_proj_mfma, which complete (stream-ordered)
    // before k_logits_mfma writes part.
    _Float16* part  = (_Float16*)aliasb;

    k_pack_frag<<<2688, 256, 0, stream>>>(Wc, Wcp, 1536, 7, RR);
    k_pack_frag<<<288, 256, 0, stream>>>(Wh + (size_t)HH * HH, Whf, 24, 48, HH);
    k_pack_frag<<<288, 256, 0, stream>>>(Wt + (size_t)HH * HH, Wtf, 24, 48, HH);
    k_pack_hid<<<1536, 256, 0, stream>>>(hid, hidb);
    k_ent_prep<<<BB * EE, 256, 0, stream>>>(hid, att, head, tail, ent_feat, ent_attn);
    k_pairw<<<NROW, 256, 0, stream>>>(ent_attn, am, pairw);
    k_fht<<<dim3(12, BB, 2), 256, 0, stream>>>(ent_feat, Wh, bh, Wt, bt, Fht);
    k_vgemm<<<dim3(64, 12), 256, 0, stream>>>(hidb, Whf, Wtf, Vhf, Vtf);
    k_proj_mfma<<<dim3(16, 12, BB), 256, 0, stream>>>(pairw, Vhf, Vtf, Fht, hb, tb);
    k_logits_mfma<<<dim3(NROW / 64, GG), 256, 0, stream>>>(hb, tb, Wcp, part);
    k_reduce<<<(NN * RR + 255) / 256, 256, 0, stream>>>(part, bc, out);
}

// Round 5
// 175.504 us; speedup vs baseline: 9.5298x; 1.6352x over previous
//
#include <hip/hip_runtime.h>
#include <cstdint>
#include <cstddef>

#define BB 4
#define LL 1024
#define HH 768
#define AA 12
#define EE 32
#define PP 992           // EE*(EE-1)
#define PPAD 1024
#define NROW (BB*PPAD)   // 4096
#define NN (BB*PP)       // 3968
#define RR 97
#define RP 112
#define GG 12
#define KG 4096

typedef __attribute__((ext_vector_type(8))) _Float16 half8;
typedef __attribute__((ext_vector_type(4))) _Float16 half4v;
typedef __attribute__((ext_vector_type(2))) _Float16 half2v;
typedef __attribute__((ext_vector_type(4))) float floatx4;

union H8u { half8 v8; half2v v2[4]; };

#define WAITVM(N) asm volatile("s_waitcnt vmcnt(" #N ")" ::: "memory")

__device__ __forceinline__ void gl_lds16(const void* g, void* l) {
    __builtin_amdgcn_global_load_lds(
        (const __attribute__((address_space(1))) unsigned int*)g,
        (__attribute__((address_space(3))) unsigned int*)l, 16, 0, 0);
}

// raw barrier: no auto vmcnt(0) drain (manual counted waits around it)
__device__ __forceinline__ void barrier_raw() {
    asm volatile("" ::: "memory");
    __builtin_amdgcn_s_barrier();
    __builtin_amdgcn_sched_barrier(0);
    asm volatile("" ::: "memory");
}

__device__ __forceinline__ int xswz96(int bid) {  // 768 blocks -> 8 XCD chunks of 96
    return (bid & 7) * 96 + (bid >> 3);
}

__device__ __forceinline__ void pair_decode(int p, int& i0, int& i1) {
    i0 = p / 31;
    int r = p - i0 * 31;
    i1 = r + (r >= i0 ? 1 : 0);
}

__device__ __forceinline__ float fast_tanh(float x) {
    float ax = fabsf(x);
    float t = __builtin_amdgcn_exp2f(ax * -2.885390082f);   // exp(-2|x|)
    float r = (1.f - t) * __builtin_amdgcn_rcpf(1.f + t);
    return copysignf(r, x);
}

// ---------------------------------------------------------------------------
// stage0 (merged, all independent):
//  [0,3072)    Wc   f32[49152][97] -> f16 MFMA B-frags, 8 r-tiles (pad zeros)
//  [3072,3360) Wh2  (rows 768..1535 of Wh) -> frag layout (48 col-tiles)
//  [3360,3648) Wt2  same
//  [3648,5184) hid  f32 -> f16 row-major
//  [5184,5440) ent_prep (be, half): ent_feat + ent_attn (gathered rows only)
// ---------------------------------------------------------------------------
__global__ __launch_bounds__(256) void k_stage0(
        const float* __restrict__ hid, const float* __restrict__ att,
        const int* __restrict__ head, const int* __restrict__ tail,
        const float* __restrict__ Wh, const float* __restrict__ Wt,
        const float* __restrict__ Wc,
        _Float16* __restrict__ hidb, _Float16* __restrict__ Whf,
        _Float16* __restrict__ Wtf, _Float16* __restrict__ Wcp,
        float* __restrict__ ent_feat, float* __restrict__ ent_attn) {
    int bid = blockIdx.x, tid = threadIdx.x;
    if (bid < 3072) {
        int idx = bid * 256 + tid;             // 786432 = 12*128*8*64
        int lane = idx & 63, frag = idx >> 6;
        int rt = frag & 7, ksg = frag >> 3;    // ksg = g*128+ks
        int c = rt * 16 + (lane & 15);
        int kb = (ksg >> 7) * KG + (ksg & 127) * 32 + (lane >> 4) * 8;
        _Float16 v[8];
        #pragma unroll
        for (int e = 0; e < 8; ++e)
            v[e] = (c < RR) ? (_Float16)Wc[(size_t)(kb + e) * RR + c] : (_Float16)0.f;
        *(half8*)(Wcp + (size_t)idx * 8) = *(const half8*)v;
    } else if (bid < 3648) {
        int which = (bid < 3360) ? 0 : 1;
        const float* src = (which ? Wt : Wh) + (size_t)HH * HH;
        _Float16* dst = which ? Wtf : Whf;
        int idx = (bid - (which ? 3360 : 3072)) * 256 + tid;   // 73728 = 24*48*64
        int lane = idx & 63, f = idx >> 6;
        int ct = f % 48, ks = f / 48;
        int c = ct * 16 + (lane & 15);
        int kb = ks * 32 + (lane >> 4) * 8;
        _Float16 v[8];
        #pragma unroll
        for (int e = 0; e < 8; ++e)
            v[e] = (_Float16)src[(size_t)(kb + e) * HH + c];
        *(half8*)(dst + (size_t)idx * 8) = *(const half8*)v;
    } else if (bid < 5184) {
        int idx = (bid - 3648) * 256 + tid;
        const float* s = hid + (size_t)idx * 8;
        float4 a = *(const float4*)s;
        float4 b = *(const float4*)(s + 4);
        half8 v = { (_Float16)a.x, (_Float16)a.y, (_Float16)a.z, (_Float16)a.w,
                    (_Float16)b.x, (_Float16)b.y, (_Float16)b.z, (_Float16)b.w };
        *(half8*)(hidb + (size_t)idx * 8) = v;
    } else {
        int q = bid - 5184;                    // 256: (be, half)
        int be = q >> 1, hf = q & 1;
        int b = be >> 5;
        int hd = head[be], tl = tail[be];
        const float* hrow = hid + ((size_t)b * LL + hd) * HH;
        const float* trow = hid + ((size_t)b * LL + tl) * HH;
        for (int hh = tid; hh < 384; hh += 256) {
            int c = hf * 384 + hh;
            ent_feat[(size_t)be * HH + c] = 0.5f * (hrow[c] + trow[c]);
        }
        const float* abase = att + (size_t)b * AA * LL * LL;
        for (int l = tid; l < 512; l += 256) {
            int ll = hf * 512 + l;
            float s = 0.f;
            #pragma unroll
            for (int a = 0; a < AA; ++a) {
                const float* ar = abase + (size_t)a * LL * LL;
                s += ar[(size_t)hd * LL + ll] + ar[(size_t)tl * LL + ll];
            }
            ent_attn[(size_t)be * LL + ll] = s * (0.5f / AA);
        }
    }
}

// ---------------------------------------------------------------------------
// stage1 (merged):
//  [0,4096)   pairw[b,p,:] = f16 normalized pair weights (padded rows zero)
//  [4096,4192) Fht[mat,b,e,:] = ent_feat @ W1 + bias  (f32, tiny)
// ---------------------------------------------------------------------------
__global__ __launch_bounds__(256) void k_stage1(
        const float* __restrict__ ent_attn, const float* __restrict__ am,
        const float* __restrict__ ent_feat,
        const float* __restrict__ Wh, const float* __restrict__ bh,
        const float* __restrict__ Wt, const float* __restrict__ bt,
        _Float16* __restrict__ pairw, float* __restrict__ Fht) {
    __shared__ float red[4];
    __shared__ float sinv;
    __shared__ float fs[EE][68];
    __shared__ float ws_[64][68];
    int tid = threadIdx.x;
    if (blockIdx.x < 4096) {
        int prow = blockIdx.x;
        int b = prow >> 10, p = prow & 1023;
        _Float16* dst = pairw + (size_t)prow * LL;
        if (p >= PP) {
            half4v z = {};
            *(half4v*)(dst + tid * 4) = z;
            return;
        }
        int i0, i1; pair_decode(p, i0, i1);
        const float* e0  = ent_attn + ((size_t)b * EE + i0) * LL;
        const float* e1  = ent_attn + ((size_t)b * EE + i1) * LL;
        const float* amr = am + (size_t)b * LL;
        float4 a = *(const float4*)(e0 + tid * 4);
        float4 c = *(const float4*)(e1 + tid * 4);
        float4 m = *(const float4*)(amr + tid * 4);
        float w0 = a.x * c.x * m.x, w1 = a.y * c.y * m.y;
        float w2 = a.z * c.z * m.z, w3 = a.w * c.w * m.w;
        float s = w0 + w1 + w2 + w3;
        #pragma unroll
        for (int off = 32; off > 0; off >>= 1) s += __shfl_down(s, off, 64);
        int lane = tid & 63, wv = tid >> 6;
        if (lane == 0) red[wv] = s;
        __syncthreads();
        if (tid == 0) sinv = 1.0f / (red[0] + red[1] + red[2] + red[3] + 1e-20f);
        __syncthreads();
        float inv = sinv;
        half4v o = { (_Float16)(w0 * inv), (_Float16)(w1 * inv),
                     (_Float16)(w2 * inv), (_Float16)(w3 * inv) };
        *(half4v*)(dst + tid * 4) = o;
    } else {
        int q = blockIdx.x - 4096;
        int ct = q % 12, b = (q / 12) % BB, mat = q / 48;
        const float* W    = mat ? Wt : Wh;
        const float* bias = mat ? bt : bh;
        int e = tid >> 3, cg = tid & 7;
        float acc[8] = {};
        for (int k0 = 0; k0 < HH; k0 += 64) {
            __syncthreads();
            #pragma unroll
            for (int it = 0; it < 2; ++it) {
                int idx = tid + it * 256;
                int ee = idx >> 4, kk = (idx & 15) * 4;
                *(float4*)(&fs[ee][kk]) =
                    *(const float4*)(ent_feat + ((size_t)b * EE + ee) * HH + k0 + kk);
            }
            #pragma unroll
            for (int it = 0; it < 4; ++it) {
                int idx = tid + it * 256;
                int kk = idx >> 4, cc = (idx & 15) * 4;
                *(float4*)(&ws_[kk][cc]) =
                    *(const float4*)(W + (size_t)(k0 + kk) * HH + ct * 64 + cc);
            }
            __syncthreads();
            #pragma unroll
            for (int kk = 0; kk < 64; ++kk) {
                float f = fs[e][kk];
                float4 w0 = *(const float4*)(&ws_[kk][cg * 8]);
                float4 w1 = *(const float4*)(&ws_[kk][cg * 8 + 4]);
                acc[0] += f * w0.x; acc[1] += f * w0.y; acc[2] += f * w0.z; acc[3] += f * w0.w;
                acc[4] += f * w1.x; acc[5] += f * w1.y; acc[6] += f * w1.z; acc[7] += f * w1.w;
            }
        }
        int cbase = ct * 64 + cg * 8;
        float* dst = Fht + (((size_t)mat * BB + b) * EE + e) * HH + cbase;
        #pragma unroll
        for (int j = 0; j < 8; ++j) dst[j] = acc[j] + bias[cbase + j];
    }
}

// ---------------------------------------------------------------------------
// vgemm: Vh = hidb@Wh2, Vt = hidb@Wt2; M=4096,K=768,N=768x2.
// 2 waves x 32 rows, 4 col-tiles, B LDS-dbuf via global_load_lds, vmcnt(6).
// Output scattered directly into proj-B fragment layout.
// ---------------------------------------------------------------------------
__global__ __launch_bounds__(128) void k_vgemm(
        const _Float16* __restrict__ hidb,
        const _Float16* __restrict__ Whf, const _Float16* __restrict__ Wtf,
        _Float16* __restrict__ Vhf, _Float16* __restrict__ Vtf) {
    int bid = xswz96(blockIdx.x);
    int cb = bid >> 6, mI = bid & 63;
    int ct0 = cb * 4;
    __shared__ __align__(16) _Float16 Bs[2][4096];
    int tid = threadIdx.x, lane = tid & 63, wid = tid >> 6;
    int r0 = wid * 32 + (lane & 15);
    int kg8 = (lane >> 4) * 8;

    const _Float16* A0 = hidb + (size_t)(mI * 64 + r0) * HH + kg8;
    const _Float16* A1 = A0 + 16 * HH;
    const char* WhB = (const char*)Whf;
    const char* WtB = (const char*)Wtf;
    char* LB = (char*)&Bs[0][0];

    half8 a0c = *(const half8*)A0;
    half8 a1c = *(const half8*)A1;
    {
        const char* hs = WhB + (size_t)ct0 * 1024;
        const char* ts = WtB + (size_t)ct0 * 1024;
        #pragma unroll
        for (int r2 = 0; r2 < 2; ++r2) {
            gl_lds16(hs + r2 * 2048 + wid * 1024 + lane * 16, LB + r2 * 2048 + wid * 1024);
            gl_lds16(ts + r2 * 2048 + wid * 1024 + lane * 16, LB + 4096 + r2 * 2048 + wid * 1024);
        }
    }
    floatx4 aH[2][4] = {}, aT[2][4] = {};
    half8 a0n = a0c, a1n = a1c;
    for (int ks = 0; ks < 24; ++ks) {
        int buf = ks & 1;
        if (ks < 23) {
            a0n = *(const half8*)(A0 + (ks + 1) * 32);
            a1n = *(const half8*)(A1 + (ks + 1) * 32);
            const char* hs = WhB + (size_t)((ks + 1) * 48 + ct0) * 1024;
            const char* ts = WtB + (size_t)((ks + 1) * 48 + ct0) * 1024;
            char* lb = LB + (buf ^ 1) * 8192;
            #pragma unroll
            for (int r2 = 0; r2 < 2; ++r2) {
                gl_lds16(hs + r2 * 2048 + wid * 1024 + lane * 16, lb + r2 * 2048 + wid * 1024);
                gl_lds16(ts + r2 * 2048 + wid * 1024 + lane * 16, lb + 4096 + r2 * 2048 + wid * 1024);
            }
            WAITVM(6);
        } else {
            WAITVM(0);
        }
        barrier_raw();
        const half8* bp = (const half8*)(LB + buf * 8192) + lane;
        #pragma unroll
        for (int ct = 0; ct < 4; ++ct) {
            half8 bvh = bp[ct * 64];
            half8 bvt = bp[256 + ct * 64];
            aH[0][ct] = __builtin_amdgcn_mfma_f32_16x16x32_f16(a0c, bvh, aH[0][ct], 0, 0, 0);
            aH[1][ct] = __builtin_amdgcn_mfma_f32_16x16x32_f16(a1c, bvh, aH[1][ct], 0, 0, 0);
            aT[0][ct] = __builtin_amdgcn_mfma_f32_16x16x32_f16(a0c, bvt, aT[0][ct], 0, 0, 0);
            aT[1][ct] = __builtin_amdgcn_mfma_f32_16x16x32_f16(a1c, bvt, aT[1][ct], 0, 0, 0);
        }
        barrier_raw();
        a0c = a0n; a1c = a1n;
    }
    int b = mI >> 4;
    int kspB = (mI & 15) * 2 + wid;
    int u = lane >> 4, rb = lane & 15;
    int estart = (u & 1) * 4;
    size_t bofs = (size_t)b * 786432;
    #pragma unroll
    for (int rs = 0; rs < 2; ++rs) {
        int laneL = (rs * 2 + (u >> 1)) * 16 + rb;
        #pragma unroll
        for (int ct = 0; ct < 4; ++ct) {
            size_t base = bofs + ((size_t)(kspB * 48 + ct0 + ct) * 64 + laneL) * 8 + estart;
            half4v hv = { (_Float16)aH[rs][ct][0], (_Float16)aH[rs][ct][1],
                          (_Float16)aH[rs][ct][2], (_Float16)aH[rs][ct][3] };
            half4v tv = { (_Float16)aT[rs][ct][0], (_Float16)aT[rs][ct][1],
                          (_Float16)aT[rs][ct][2], (_Float16)aT[rs][ct][3] };
            *(half4v*)(Vhf + base) = hv;
            *(half4v*)(Vtf + base) = tv;
        }
    }
}

// ---------------------------------------------------------------------------
// proj: h = tanh(Fh[i0] + pairw@Vh), t = tanh(Ft[i1] + pairw@Vt).
// Same 2-wave/32-row/4-ct structure; A from global (prefetched regs).
// ---------------------------------------------------------------------------
__global__ __launch_bounds__(128) void k_proj_mfma(
        const _Float16* __restrict__ pairw,
        const _Float16* __restrict__ Vhf, const _Float16* __restrict__ Vtf,
        const float* __restrict__ Fht,
        _Float16* __restrict__ hb, _Float16* __restrict__ tb) {
    int bid = xswz96(blockIdx.x);
    int bc = bid >> 4, mI = bid & 15;       // bc = b*12+cb
    int b = bc / 12, cb = bc - b * 12;
    int ct0 = cb * 4;
    __shared__ __align__(16) _Float16 Bs[2][4096];
    int tid = threadIdx.x, lane = tid & 63, wid = tid >> 6;
    int r0 = wid * 32 + (lane & 15);
    int kg8 = (lane >> 4) * 8;

    const _Float16* A0 = pairw + (size_t)(b * PPAD + mI * 64 + r0) * LL + kg8;
    const _Float16* A1 = A0 + 16 * LL;
    const char* VhB = (const char*)(Vhf + (size_t)b * 786432);
    const char* VtB = (const char*)(Vtf + (size_t)b * 786432);
    char* LB = (char*)&Bs[0][0];

    half8 a0c = *(const half8*)A0;
    half8 a1c = *(const half8*)A1;
    {
        const char* hs = VhB + (size_t)ct0 * 1024;
        const char* ts = VtB + (size_t)ct0 * 1024;
        #pragma unroll
        for (int r2 = 0; r2 < 2; ++r2) {
            gl_lds16(hs + r2 * 2048 + wid * 1024 + lane * 16, LB + r2 * 2048 + wid * 1024);
            gl_lds16(ts + r2 * 2048 + wid * 1024 + lane * 16, LB + 4096 + r2 * 2048 + wid * 1024);
        }
    }
    floatx4 aH[2][4] = {}, aT[2][4] = {};
    half8 a0n = a0c, a1n = a1c;
    for (int ks = 0; ks < 32; ++ks) {
        int buf = ks & 1;
        if (ks < 31) {
            a0n = *(const half8*)(A0 + (ks + 1) * 32);
            a1n = *(const half8*)(A1 + (ks + 1) * 32);
            const char* hs = VhB + (size_t)((ks + 1) * 48 + ct0) * 1024;
            const char* ts = VtB + (size_t)((ks + 1) * 48 + ct0) * 1024;
            char* lb = LB + (buf ^ 1) * 8192;
            #pragma unroll
            for (int r2 = 0; r2 < 2; ++r2) {
                gl_lds16(hs + r2 * 2048 + wid * 1024 + lane * 16, lb + r2 * 2048 + wid * 1024);
                gl_lds16(ts + r2 * 2048 + wid * 1024 + lane * 16, lb + 4096 + r2 * 2048 + wid * 1024);
            }
            WAITVM(6);
        } else {
            WAITVM(0);
        }
        barrier_raw();
        const half8* bp = (const half8*)(LB + buf * 8192) + lane;
        #pragma unroll
        for (int ct = 0; ct < 4; ++ct) {
            half8 bvh = bp[ct * 64];
            half8 bvt = bp[256 + ct * 64];
            aH[0][ct] = __builtin_amdgcn_mfma_f32_16x16x32_f16(a0c, bvh, aH[0][ct], 0, 0, 0);
            aH[1][ct] = __builtin_amdgcn_mfma_f32_16x16x32_f16(a1c, bvh, aH[1][ct], 0, 0, 0);
            aT[0][ct] = __builtin_amdgcn_mfma_f32_16x16x32_f16(a0c, bvt, aT[0][ct], 0, 0, 0);
            aT[1][ct] = __builtin_amdgcn_mfma_f32_16x16x32_f16(a1c, bvt, aT[1][ct], 0, 0, 0);
        }
        barrier_raw();
        a0c = a0n; a1c = a1n;
    }
    const float* FhB = Fht + (size_t)b * EE * HH;
    const float* FtB = Fht + (size_t)(BB + b) * EE * HH;
    int u = lane >> 4, rb = lane & 15;
    #pragma unroll
    for (int rs = 0; rs < 2; ++rs) {
        int pb = mI * 64 + wid * 32 + rs * 16 + u * 4;
        int i0a[4], i1a[4];
        #pragma unroll
        for (int q = 0; q < 4; ++q) {
            int p = pb + q;
            if (p < PP) pair_decode(p, i0a[q], i1a[q]);
            else { i0a[q] = -1; i1a[q] = -1; }
        }
        #pragma unroll
        for (int ct = 0; ct < 4; ++ct) {
            int c = (ct0 + ct) * 16 + rb;
            #pragma unroll
            for (int q = 0; q < 4; ++q) {
                size_t row = (size_t)b * PPAD + pb + q;
                _Float16 hv = (_Float16)0.f, tv = (_Float16)0.f;
                if (i0a[q] >= 0) {
                    hv = (_Float16)fast_tanh(aH[rs][ct][q] + FhB[(size_t)i0a[q] * HH + c]);
                    tv = (_Float16)fast_tanh(aT[rs][ct][q] + FtB[(size_t)i1a[q] * HH + c]);
                }
                hb[row * HH + c] = hv;
                tb[row * HH + c] = tv;
            }
        }
    }
}

// ---------------------------------------------------------------------------
// logits: part[g,n,r] = sum_{i,j} h[n,g64+i]*t[n,g64+j]*Wc[(g64+i)*64+j,r]
// A built in-register (pk_mul) from f16 LDS tiles; B (Wcp) LDS-dbuf staged.
// 2 waves x 32 rows x 112 cols; K=4096/g; vmcnt(4) counted pipeline.
// ---------------------------------------------------------------------------
__global__ __launch_bounds__(128) void k_logits_mfma(
        const _Float16* __restrict__ hb, const _Float16* __restrict__ tb,
        const _Float16* __restrict__ Wcp, _Float16* __restrict__ part) {
    int bid = xswz96(blockIdx.x);
    int g = bid >> 6, nb = bid & 63;
    int n0 = nb * 64;
    __shared__ __align__(16) _Float16 hT[64][72];
    __shared__ __align__(16) _Float16 tT[8][64][8];
    __shared__ __align__(16) _Float16 Bs[2][4096];
    int tid = threadIdx.x, lane = tid & 63, wid = tid >> 6;

    #pragma unroll
    for (int it = 0; it < 4; ++it) {
        int idx = tid + it * 128;
        int row = idx >> 3, c8 = (idx & 7) * 8;
        half8 hv = *(const half8*)(hb + (size_t)(n0 + row) * HH + g * 64 + c8);
        half8 tv = *(const half8*)(tb + (size_t)(n0 + row) * HH + g * 64 + c8);
        *(half8*)&hT[row][c8] = hv;
        *(half8*)&tT[idx & 7][row][0] = tv;
    }
    __syncthreads();   // tiles visible (full drain OK, once)

    const char* WcB = (const char*)Wcp + ((size_t)g << 20);  // g*128*8192
    char* LB = (char*)&Bs[0][0];
    {
        #pragma unroll
        for (int r = 0; r < 4; ++r)
            gl_lds16(WcB + r * 2048 + wid * 1024 + lane * 16, LB + r * 2048 + wid * 1024);
    }
    int r0 = wid * 32 + (lane & 15);
    int kgrp = lane >> 4;
    floatx4 acc[2][7] = {};

    #pragma unroll 2
    for (int ks = 0; ks < 128; ++ks) {
        int buf = ks & 1;
        // A-fragments (independent of Bs) — hide under stage wait
        int i = ks >> 1;
        int ch = (ks & 1) * 4 + kgrp;
        _Float16 h0 = hT[r0][i], h1 = hT[r0 + 16][i];
        H8u t0u, t1u, a0, a1;
        t0u.v8 = *(const half8*)&tT[ch][r0][0];
        t1u.v8 = *(const half8*)&tT[ch][r0 + 16][0];
        half2v h02 = { h0, h0 }, h12 = { h1, h1 };
        #pragma unroll
        for (int q = 0; q < 4; ++q) {
            a0.v2[q] = h02 * t0u.v2[q];
            a1.v2[q] = h12 * t1u.v2[q];
        }
        if (ks < 127) {
            const char* sn = WcB + ((size_t)(ks + 1) << 13);
            char* lb = LB + (buf ^ 1) * 8192;
            #pragma unroll
            for (int r = 0; r < 4; ++r)
                gl_lds16(sn + r * 2048 + wid * 1024 + lane * 16, lb + r * 2048 + wid * 1024);
            WAITVM(4);
        } else {
            WAITVM(0);
        }
        barrier_raw();
        const half8* bp = (const half8*)(LB + buf * 8192) + lane;
        #pragma unroll
        for (int rt = 0; rt < 7; ++rt) {
            half8 bv = bp[rt * 64];
            acc[0][rt] = __builtin_amdgcn_mfma_f32_16x16x32_f16(a0.v8, bv, acc[0][rt], 0, 0, 0);
            acc[1][rt] = __builtin_amdgcn_mfma_f32_16x16x32_f16(a1.v8, bv, acc[1][rt], 0, 0, 0);
        }
        barrier_raw();
    }
    int rb = lane & 15, u = lane >> 4;
    #pragma unroll
    for (int rs = 0; rs < 2; ++rs) {
        int nbase = n0 + wid * 32 + rs * 16 + u * 4;
        #pragma unroll
        for (int rt = 0; rt < 7; ++rt)
            #pragma unroll
            for (int q = 0; q < 4; ++q)
                part[((size_t)g * NROW + nbase + q) * RP + rt * 16 + rb] =
                    (_Float16)acc[rs][rt][q];
    }
}

// ---------------------------------------------------------------------------
// reduce: logits[n,r] = bc[r] + sum_g part[g, rowp(n), r]
// ---------------------------------------------------------------------------
__global__ __launch_bounds__(256) void k_reduce(
        const _Float16* __restrict__ part, const float* __restrict__ bc,
        float* __restrict__ out) {
    int idx = blockIdx.x * 256 + threadIdx.x;
    if (idx >= NN * RR) return;
    int n = idx / RR;
    int r = idx - n * RR;
    int b = n / PP, p = n - b * PP;
    size_t rowp = (size_t)b * PPAD + p;
    float s = bc[r];
    #pragma unroll
    for (int g = 0; g < GG; ++g)
        s += (float)part[((size_t)g * NROW + rowp) * RP + r];
    out[idx] = s;
}

// ---------------------------------------------------------------------------
extern "C" void kernel_launch(void* const* d_in, const int* in_sizes, int n_in,
                              void* d_out, int out_size, void* d_ws, size_t ws_size,
                              hipStream_t stream) {
    const float* hid  = (const float*)d_in[0];
    const float* att  = (const float*)d_in[1];
    const float* am   = (const float*)d_in[2];
    const int*   head = (const int*)d_in[3];
    const int*   tail = (const int*)d_in[4];
    const float* Wh   = (const float*)d_in[5];
    const float* bh   = (const float*)d_in[6];
    const float* Wt   = (const float*)d_in[7];
    const float* bt   = (const float*)d_in[8];
    const float* Wc   = (const float*)d_in[9];
    const float* bc   = (const float*)d_in[10];
    float* out = (float*)d_out;

    // ---- workspace (~56 MB; part aliases buffers dead before k_logits) ----
    char* w = (char*)d_ws;
    _Float16* Wcp = (_Float16*)w;  w += (size_t)GG * 128 * 8 * 64 * 8 * 2;  // 12.58 MB
    _Float16* Vhf = (_Float16*)w;  w += (size_t)BB * 786432 * 2;            //  6.29 MB
    _Float16* Vtf = (_Float16*)w;  w += (size_t)BB * 786432 * 2;
    _Float16* hbv = (_Float16*)w;  w += (size_t)NROW * HH * 2;              //  6.29 MB
    _Float16* tbv = (_Float16*)w;  w += (size_t)NROW * HH * 2;
    float* Fht      = (float*)w;   w += (size_t)2 * BB * EE * HH * 4;       //  0.79 MB
    float* ent_feat = (float*)w;   w += (size_t)BB * EE * HH * 4;
    float* ent_attn = (float*)w;   w += (size_t)BB * EE * LL * 4;
    char* alias = w;
    _Float16* hidb  = (_Float16*)alias;                                     //  6.29 MB
    _Float16* Whf   = (_Float16*)(alias + 6291456);                         //  1.18 MB
    _Float16* Wtf   = (_Float16*)(alias + 6291456 + 1179648);
    _Float16* pairw = (_Float16*)(alias + 6291456 + 2 * 1179648);           //  8.39 MB
    _Float16* part  = (_Float16*)alias;  // 11.01 MB, overlaps hidb/Whf/Wtf/pairw-prefix:
                                         // all last-read before k_logits writes (stream order)

    k_stage0<<<5440, 256, 0, stream>>>(hid, att, head, tail, Wh, Wt, Wc,
                                       hidb, Whf, Wtf, Wcp, ent_feat, ent_attn);
    k_stage1<<<4192, 256, 0, stream>>>(ent_attn, am, ent_feat, Wh, bh, Wt, bt, pairw, Fht);
    k_vgemm<<<768, 128, 0, stream>>>(hidb, Whf, Wtf, Vhf, Vtf);
    k_proj_mfma<<<768, 128, 0, stream>>>(pairw, Vhf, Vtf, Fht, hbv, tbv);
    k_logits_mfma<<<768, 128, 0, stream>>>(hbv, tbv, Wcp, part);
    k_reduce<<<1504, 256, 0, stream>>>(part, bc, out);
}

// Round 6
// 168.866 us; speedup vs baseline: 9.9044x; 1.0393x over previous
//
#include <hip/hip_runtime.h>
#include <cstdint>
#include <cstddef>

#define BB 4
#define LL 1024
#define HH 768
#define AA 12
#define EE 32
#define PP 992           // EE*(EE-1)
#define PPAD 1024
#define NROW (BB*PPAD)   // 4096
#define NN (BB*PP)       // 3968
#define RR 97
#define RP 112
#define GG 12
#define KG 4096

typedef __attribute__((ext_vector_type(8))) _Float16 half8;
typedef __attribute__((ext_vector_type(4))) _Float16 half4v;
typedef __attribute__((ext_vector_type(2))) _Float16 half2v;
typedef __attribute__((ext_vector_type(4))) float floatx4;

union H8u { half8 v8; half2v v2[4]; };

#define WAITVM(N) asm volatile("s_waitcnt vmcnt(" #N ")" ::: "memory")

__device__ __forceinline__ void gl_lds16(const void* g, void* l) {
    __builtin_amdgcn_global_load_lds(
        (const __attribute__((address_space(1))) unsigned int*)g,
        (__attribute__((address_space(3))) unsigned int*)l, 16, 0, 0);
}

// raw barrier: no auto vmcnt(0) drain (manual counted waits around it)
__device__ __forceinline__ void barrier_raw() {
    asm volatile("" ::: "memory");
    __builtin_amdgcn_s_barrier();
    __builtin_amdgcn_sched_barrier(0);
    asm volatile("" ::: "memory");
}

__device__ __forceinline__ int xswz96(int bid) {  // 768 blocks -> 8 XCD chunks of 96
    return (bid & 7) * 96 + (bid >> 3);
}

__device__ __forceinline__ void pair_decode(int p, int& i0, int& i1) {
    i0 = p / 31;
    int r = p - i0 * 31;
    i1 = r + (r >= i0 ? 1 : 0);
}

__device__ __forceinline__ float fast_tanh(float x) {
    float ax = fabsf(x);
    float t = __builtin_amdgcn_exp2f(ax * -2.885390082f);   // exp(-2|x|)
    float r = (1.f - t) * __builtin_amdgcn_rcpf(1.f + t);
    return copysignf(r, x);
}

// ---------------------------------------------------------------------------
// stage0 (merged, all independent):
//  [0,3072)    Wc   f32[49152][97] -> f16 MFMA B-frags, 8 r-tiles (pad zeros)
//  [3072,3360) Wh2  (rows 768..1535 of Wh) -> frag layout (48 col-tiles)
//  [3360,3648) Wt2  same
//  [3648,5184) hid  f32 -> f16 row-major
//  [5184,5440) ent_prep (be, half): ent_feat + ent_attn (gathered rows only)
// ---------------------------------------------------------------------------
__global__ __launch_bounds__(256) void k_stage0(
        const float* __restrict__ hid, const float* __restrict__ att,
        const int* __restrict__ head, const int* __restrict__ tail,
        const float* __restrict__ Wh, const float* __restrict__ Wt,
        const float* __restrict__ Wc,
        _Float16* __restrict__ hidb, _Float16* __restrict__ Whf,
        _Float16* __restrict__ Wtf, _Float16* __restrict__ Wcp,
        float* __restrict__ ent_feat, float* __restrict__ ent_attn) {
    int bid = blockIdx.x, tid = threadIdx.x;
    if (bid < 3072) {
        int idx = bid * 256 + tid;             // 786432 = 12*128*8*64
        int lane = idx & 63, frag = idx >> 6;
        int rt = frag & 7, ksg = frag >> 3;    // ksg = g*128+ks
        int c = rt * 16 + (lane & 15);
        int kb = (ksg >> 7) * KG + (ksg & 127) * 32 + (lane >> 4) * 8;
        _Float16 v[8];
        #pragma unroll
        for (int e = 0; e < 8; ++e)
            v[e] = (c < RR) ? (_Float16)Wc[(size_t)(kb + e) * RR + c] : (_Float16)0.f;
        *(half8*)(Wcp + (size_t)idx * 8) = *(const half8*)v;
    } else if (bid < 3648) {
        int which = (bid < 3360) ? 0 : 1;
        const float* src = (which ? Wt : Wh) + (size_t)HH * HH;
        _Float16* dst = which ? Wtf : Whf;
        int idx = (bid - (which ? 3360 : 3072)) * 256 + tid;   // 73728 = 24*48*64
        int lane = idx & 63, f = idx >> 6;
        int ct = f % 48, ks = f / 48;
        int c = ct * 16 + (lane & 15);
        int kb = ks * 32 + (lane >> 4) * 8;
        _Float16 v[8];
        #pragma unroll
        for (int e = 0; e < 8; ++e)
            v[e] = (_Float16)src[(size_t)(kb + e) * HH + c];
        *(half8*)(dst + (size_t)idx * 8) = *(const half8*)v;
    } else if (bid < 5184) {
        int idx = (bid - 3648) * 256 + tid;
        const float* s = hid + (size_t)idx * 8;
        float4 a = *(const float4*)s;
        float4 b = *(const float4*)(s + 4);
        half8 v = { (_Float16)a.x, (_Float16)a.y, (_Float16)a.z, (_Float16)a.w,
                    (_Float16)b.x, (_Float16)b.y, (_Float16)b.z, (_Float16)b.w };
        *(half8*)(hidb + (size_t)idx * 8) = v;
    } else {
        int q = bid - 5184;                    // 256: (be, half)
        int be = q >> 1, hf = q & 1;
        int b = be >> 5;
        int hd = head[be], tl = tail[be];
        const float* hrow = hid + ((size_t)b * LL + hd) * HH;
        const float* trow = hid + ((size_t)b * LL + tl) * HH;
        for (int hh = tid; hh < 384; hh += 256) {
            int c = hf * 384 + hh;
            ent_feat[(size_t)be * HH + c] = 0.5f * (hrow[c] + trow[c]);
        }
        const float* abase = att + (size_t)b * AA * LL * LL;
        for (int l = tid; l < 512; l += 256) {
            int ll = hf * 512 + l;
            float s = 0.f;
            #pragma unroll
            for (int a = 0; a < AA; ++a) {
                const float* ar = abase + (size_t)a * LL * LL;
                s += ar[(size_t)hd * LL + ll] + ar[(size_t)tl * LL + ll];
            }
            ent_attn[(size_t)be * LL + ll] = s * (0.5f / AA);
        }
    }
}

// ---------------------------------------------------------------------------
// stage1 (merged):
//  [0,4096)   pairw[b,p,:] = f16 normalized pair weights (padded rows zero)
//  [4096,4192) Fht[mat,b,e,:] = ent_feat @ W1 + bias  (f32, tiny)
// ---------------------------------------------------------------------------
__global__ __launch_bounds__(256) void k_stage1(
        const float* __restrict__ ent_attn, const float* __restrict__ am,
        const float* __restrict__ ent_feat,
        const float* __restrict__ Wh, const float* __restrict__ bh,
        const float* __restrict__ Wt, const float* __restrict__ bt,
        _Float16* __restrict__ pairw, float* __restrict__ Fht) {
    __shared__ float red[4];
    __shared__ float sinv;
    __shared__ float fs[EE][68];
    __shared__ float ws_[64][68];
    int tid = threadIdx.x;
    if (blockIdx.x < 4096) {
        int prow = blockIdx.x;
        int b = prow >> 10, p = prow & 1023;
        _Float16* dst = pairw + (size_t)prow * LL;
        if (p >= PP) {
            half4v z = {};
            *(half4v*)(dst + tid * 4) = z;
            return;
        }
        int i0, i1; pair_decode(p, i0, i1);
        const float* e0  = ent_attn + ((size_t)b * EE + i0) * LL;
        const float* e1  = ent_attn + ((size_t)b * EE + i1) * LL;
        const float* amr = am + (size_t)b * LL;
        float4 a = *(const float4*)(e0 + tid * 4);
        float4 c = *(const float4*)(e1 + tid * 4);
        float4 m = *(const float4*)(amr + tid * 4);
        float w0 = a.x * c.x * m.x, w1 = a.y * c.y * m.y;
        float w2 = a.z * c.z * m.z, w3 = a.w * c.w * m.w;
        float s = w0 + w1 + w2 + w3;
        #pragma unroll
        for (int off = 32; off > 0; off >>= 1) s += __shfl_down(s, off, 64);
        int lane = tid & 63, wv = tid >> 6;
        if (lane == 0) red[wv] = s;
        __syncthreads();
        if (tid == 0) sinv = 1.0f / (red[0] + red[1] + red[2] + red[3] + 1e-20f);
        __syncthreads();
        float inv = sinv;
        half4v o = { (_Float16)(w0 * inv), (_Float16)(w1 * inv),
                     (_Float16)(w2 * inv), (_Float16)(w3 * inv) };
        *(half4v*)(dst + tid * 4) = o;
    } else {
        int q = blockIdx.x - 4096;
        int ct = q % 12, b = (q / 12) % BB, mat = q / 48;
        const float* W    = mat ? Wt : Wh;
        const float* bias = mat ? bt : bh;
        int e = tid >> 3, cg = tid & 7;
        float acc[8] = {};
        for (int k0 = 0; k0 < HH; k0 += 64) {
            __syncthreads();
            #pragma unroll
            for (int it = 0; it < 2; ++it) {
                int idx = tid + it * 256;
                int ee = idx >> 4, kk = (idx & 15) * 4;
                *(float4*)(&fs[ee][kk]) =
                    *(const float4*)(ent_feat + ((size_t)b * EE + ee) * HH + k0 + kk);
            }
            #pragma unroll
            for (int it = 0; it < 4; ++it) {
                int idx = tid + it * 256;
                int kk = idx >> 4, cc = (idx & 15) * 4;
                *(float4*)(&ws_[kk][cc]) =
                    *(const float4*)(W + (size_t)(k0 + kk) * HH + ct * 64 + cc);
            }
            __syncthreads();
            #pragma unroll
            for (int kk = 0; kk < 64; ++kk) {
                float f = fs[e][kk];
                float4 w0 = *(const float4*)(&ws_[kk][cg * 8]);
                float4 w1 = *(const float4*)(&ws_[kk][cg * 8 + 4]);
                acc[0] += f * w0.x; acc[1] += f * w0.y; acc[2] += f * w0.z; acc[3] += f * w0.w;
                acc[4] += f * w1.x; acc[5] += f * w1.y; acc[6] += f * w1.z; acc[7] += f * w1.w;
            }
        }
        int cbase = ct * 64 + cg * 8;
        float* dst = Fht + (((size_t)mat * BB + b) * EE + e) * HH + cbase;
        #pragma unroll
        for (int j = 0; j < 8; ++j) dst[j] = acc[j] + bias[cbase + j];
    }
}

// ---------------------------------------------------------------------------
// vgemm: Vh = hidb@Wh2, Vt = hidb@Wt2; M=4096,K=768,N=768x2.
// 2 waves x 32 rows, 4 col-tiles. 4-buffer depth-2 LDS pipeline, counted
// vmcnt, ONE barrier per K-step. Output scattered into proj-B frag layout.
// ---------------------------------------------------------------------------
__global__ __launch_bounds__(128) void k_vgemm(
        const _Float16* __restrict__ hidb,
        const _Float16* __restrict__ Whf, const _Float16* __restrict__ Wtf,
        _Float16* __restrict__ Vhf, _Float16* __restrict__ Vtf) {
    int bid = xswz96(blockIdx.x);
    int cb = bid >> 6, mI = bid & 63;
    int ct0 = cb * 4;
    __shared__ __align__(16) _Float16 Bs[4][4096];
    int tid = threadIdx.x, lane = tid & 63, wid = tid >> 6;
    int r0 = wid * 32 + (lane & 15);
    int kg8 = (lane >> 4) * 8;

    const _Float16* A0 = hidb + (size_t)(mI * 64 + r0) * HH + kg8;
    const _Float16* A1 = A0 + 16 * HH;
    const char* WhB = (const char*)Whf + (size_t)ct0 * 1024;
    const char* WtB = (const char*)Wtf + (size_t)ct0 * 1024;
    char* LB = (char*)&Bs[0][0];
    int lo = wid * 2048 + lane * 16;   // global-side per-lane offset
    int ld = wid * 2048;               // LDS-side wave-uniform base

    // prologue: lds(0), A(0), lds(1)   (count-ordering matters)
    #pragma unroll
    for (int j = 0; j < 2; ++j) {
        gl_lds16(WhB + j * 1024 + lo, LB + j * 1024 + ld);
        gl_lds16(WtB + j * 1024 + lo, LB + 4096 + j * 1024 + ld);
    }
    half8 a0c = *(const half8*)A0;
    half8 a1c = *(const half8*)A1;
    {
        const char* hs = WhB + 49152;   // step 1: +48*1024
        const char* ts = WtB + 49152;
        #pragma unroll
        for (int j = 0; j < 2; ++j) {
            gl_lds16(hs + j * 1024 + lo, LB + 8192 + j * 1024 + ld);
            gl_lds16(ts + j * 1024 + lo, LB + 8192 + 4096 + j * 1024 + ld);
        }
    }
    floatx4 aH[2][4] = {}, aT[2][4] = {};
    half8 a0n = a0c, a1n = a1c;
    for (int ks = 0; ks < 24; ++ks) {
        int buf = ks & 3;
        if (ks < 23) {
            a0n = *(const half8*)(A0 + (ks + 1) * 32);
            a1n = *(const half8*)(A1 + (ks + 1) * 32);
        }
        if (ks < 22) {
            const char* hs = WhB + (size_t)(ks + 2) * 49152;
            const char* ts = WtB + (size_t)(ks + 2) * 49152;
            char* lb = LB + ((ks + 2) & 3) * 8192;
            #pragma unroll
            for (int j = 0; j < 2; ++j) {
                gl_lds16(hs + j * 1024 + lo, lb + j * 1024 + ld);
                gl_lds16(ts + j * 1024 + lo, lb + 4096 + j * 1024 + ld);
            }
            WAITVM(12);
        } else if (ks == 22) { WAITVM(8); } else { WAITVM(2); }
        barrier_raw();
        const half8* bp = (const half8*)(LB + buf * 8192) + lane;
        __builtin_amdgcn_s_setprio(1);
        #pragma unroll
        for (int ct = 0; ct < 4; ++ct) {
            half8 bvh = bp[ct * 64];
            half8 bvt = bp[256 + ct * 64];
            aH[0][ct] = __builtin_amdgcn_mfma_f32_16x16x32_f16(a0c, bvh, aH[0][ct], 0, 0, 0);
            aH[1][ct] = __builtin_amdgcn_mfma_f32_16x16x32_f16(a1c, bvh, aH[1][ct], 0, 0, 0);
            aT[0][ct] = __builtin_amdgcn_mfma_f32_16x16x32_f16(a0c, bvt, aT[0][ct], 0, 0, 0);
            aT[1][ct] = __builtin_amdgcn_mfma_f32_16x16x32_f16(a1c, bvt, aT[1][ct], 0, 0, 0);
        }
        __builtin_amdgcn_s_setprio(0);
        a0c = a0n; a1c = a1n;
    }
    int b = mI >> 4;
    int kspB = (mI & 15) * 2 + wid;
    int u = lane >> 4, rb = lane & 15;
    int estart = (u & 1) * 4;
    size_t bofs = (size_t)b * 786432;
    #pragma unroll
    for (int rs = 0; rs < 2; ++rs) {
        int laneL = (rs * 2 + (u >> 1)) * 16 + rb;
        #pragma unroll
        for (int ct = 0; ct < 4; ++ct) {
            size_t base = bofs + ((size_t)(kspB * 48 + ct0 + ct) * 64 + laneL) * 8 + estart;
            half4v hv = { (_Float16)aH[rs][ct][0], (_Float16)aH[rs][ct][1],
                          (_Float16)aH[rs][ct][2], (_Float16)aH[rs][ct][3] };
            half4v tv = { (_Float16)aT[rs][ct][0], (_Float16)aT[rs][ct][1],
                          (_Float16)aT[rs][ct][2], (_Float16)aT[rs][ct][3] };
            *(half4v*)(Vhf + base) = hv;
            *(half4v*)(Vtf + base) = tv;
        }
    }
}

// ---------------------------------------------------------------------------
// proj: h = tanh(Fh[i0] + pairw@Vh), t = tanh(Ft[i1] + pairw@Vt).
// Same 2-wave/32-row/4-ct structure; 4-buffer depth-2 pipeline.
// ---------------------------------------------------------------------------
__global__ __launch_bounds__(128) void k_proj_mfma(
        const _Float16* __restrict__ pairw,
        const _Float16* __restrict__ Vhf, const _Float16* __restrict__ Vtf,
        const float* __restrict__ Fht,
        _Float16* __restrict__ hb, _Float16* __restrict__ tb) {
    int bid = xswz96(blockIdx.x);
    int bc = bid >> 4, mI = bid & 15;       // bc = b*12+cb
    int b = bc / 12, cb = bc - b * 12;
    int ct0 = cb * 4;
    __shared__ __align__(16) _Float16 Bs[4][4096];
    int tid = threadIdx.x, lane = tid & 63, wid = tid >> 6;
    int r0 = wid * 32 + (lane & 15);
    int kg8 = (lane >> 4) * 8;

    const _Float16* A0 = pairw + (size_t)(b * PPAD + mI * 64 + r0) * LL + kg8;
    const _Float16* A1 = A0 + 16 * LL;
    const char* VhB = (const char*)(Vhf + (size_t)b * 786432) + (size_t)ct0 * 1024;
    const char* VtB = (const char*)(Vtf + (size_t)b * 786432) + (size_t)ct0 * 1024;
    char* LB = (char*)&Bs[0][0];
    int lo = wid * 2048 + lane * 16;
    int ld = wid * 2048;

    #pragma unroll
    for (int j = 0; j < 2; ++j) {
        gl_lds16(VhB + j * 1024 + lo, LB + j * 1024 + ld);
        gl_lds16(VtB + j * 1024 + lo, LB + 4096 + j * 1024 + ld);
    }
    half8 a0c = *(const half8*)A0;
    half8 a1c = *(const half8*)A1;
    {
        const char* hs = VhB + 49152;
        const char* ts = VtB + 49152;
        #pragma unroll
        for (int j = 0; j < 2; ++j) {
            gl_lds16(hs + j * 1024 + lo, LB + 8192 + j * 1024 + ld);
            gl_lds16(ts + j * 1024 + lo, LB + 8192 + 4096 + j * 1024 + ld);
        }
    }
    floatx4 aH[2][4] = {}, aT4[2][4] = {};
    half8 a0n = a0c, a1n = a1c;
    for (int ks = 0; ks < 32; ++ks) {
        int buf = ks & 3;
        if (ks < 31) {
            a0n = *(const half8*)(A0 + (ks + 1) * 32);
            a1n = *(const half8*)(A1 + (ks + 1) * 32);
        }
        if (ks < 30) {
            const char* hs = VhB + (size_t)(ks + 2) * 49152;
            const char* ts = VtB + (size_t)(ks + 2) * 49152;
            char* lb = LB + ((ks + 2) & 3) * 8192;
            #pragma unroll
            for (int j = 0; j < 2; ++j) {
                gl_lds16(hs + j * 1024 + lo, lb + j * 1024 + ld);
                gl_lds16(ts + j * 1024 + lo, lb + 4096 + j * 1024 + ld);
            }
            WAITVM(12);
        } else if (ks == 30) { WAITVM(8); } else { WAITVM(2); }
        barrier_raw();
        const half8* bp = (const half8*)(LB + buf * 8192) + lane;
        __builtin_amdgcn_s_setprio(1);
        #pragma unroll
        for (int ct = 0; ct < 4; ++ct) {
            half8 bvh = bp[ct * 64];
            half8 bvt = bp[256 + ct * 64];
            aH[0][ct]  = __builtin_amdgcn_mfma_f32_16x16x32_f16(a0c, bvh, aH[0][ct], 0, 0, 0);
            aH[1][ct]  = __builtin_amdgcn_mfma_f32_16x16x32_f16(a1c, bvh, aH[1][ct], 0, 0, 0);
            aT4[0][ct] = __builtin_amdgcn_mfma_f32_16x16x32_f16(a0c, bvt, aT4[0][ct], 0, 0, 0);
            aT4[1][ct] = __builtin_amdgcn_mfma_f32_16x16x32_f16(a1c, bvt, aT4[1][ct], 0, 0, 0);
        }
        __builtin_amdgcn_s_setprio(0);
        a0c = a0n; a1c = a1n;
    }
    const float* FhB = Fht + (size_t)b * EE * HH;
    const float* FtB = Fht + (size_t)(BB + b) * EE * HH;
    int u = lane >> 4, rb = lane & 15;
    #pragma unroll
    for (int rs = 0; rs < 2; ++rs) {
        int pb = mI * 64 + wid * 32 + rs * 16 + u * 4;
        int i0a[4], i1a[4];
        #pragma unroll
        for (int q = 0; q < 4; ++q) {
            int p = pb + q;
            if (p < PP) pair_decode(p, i0a[q], i1a[q]);
            else { i0a[q] = -1; i1a[q] = -1; }
        }
        #pragma unroll
        for (int ct = 0; ct < 4; ++ct) {
            int c = (ct0 + ct) * 16 + rb;
            #pragma unroll
            for (int q = 0; q < 4; ++q) {
                size_t row = (size_t)b * PPAD + pb + q;
                _Float16 hv = (_Float16)0.f, tv = (_Float16)0.f;
                if (i0a[q] >= 0) {
                    hv = (_Float16)fast_tanh(aH[rs][ct][q]  + FhB[(size_t)i0a[q] * HH + c]);
                    tv = (_Float16)fast_tanh(aT4[rs][ct][q] + FtB[(size_t)i1a[q] * HH + c]);
                }
                hb[row * HH + c] = hv;
                tb[row * HH + c] = tv;
            }
        }
    }
}

// ---------------------------------------------------------------------------
// logits: part[g,n,r] = sum_{i,j} h[n,g64+i]*t[n,g64+j]*Wc[(g64+i)*64+j,r]
// 4 waves x 32 rows = 128 rows/block (halves Wcp L2 re-streaming),
// 4-buffer depth-2 pipeline, counted vmcnt(4), one barrier per K-step.
// ---------------------------------------------------------------------------
__global__ __launch_bounds__(256) void k_logits_mfma(
        const _Float16* __restrict__ hb, const _Float16* __restrict__ tb,
        const _Float16* __restrict__ Wcp, _Float16* __restrict__ part) {
    int bid = (blockIdx.x & 7) * 48 + (blockIdx.x >> 3);   // 384 blocks, 8 XCD chunks
    int g = bid >> 5, nb = bid & 31;
    int n0 = nb * 128;
    __shared__ __align__(16) _Float16 hTT[8][128][8];   // [col-chunk][row][8]
    __shared__ __align__(16) _Float16 tT[8][128][8];
    __shared__ __align__(16) _Float16 Bs[4][4096];
    int tid = threadIdx.x, lane = tid & 63, wid = tid >> 6;

    #pragma unroll
    for (int it = 0; it < 4; ++it) {
        int idx = tid + it * 256;
        int row = idx >> 3, c8 = (idx & 7) * 8;
        half8 hv = *(const half8*)(hb + (size_t)(n0 + row) * HH + g * 64 + c8);
        half8 tv = *(const half8*)(tb + (size_t)(n0 + row) * HH + g * 64 + c8);
        *(half8*)&hTT[idx & 7][row][0] = hv;
        *(half8*)&tT[idx & 7][row][0] = tv;
    }
    __syncthreads();   // tiles visible (full drain OK, once)

    const char* WcB = (const char*)Wcp + ((size_t)g << 20);  // g*128*8192
    char* LB = (char*)&Bs[0][0];
    int lo = wid * 2048 + lane * 16;
    int ld = wid * 2048;
    #pragma unroll
    for (int s = 0; s < 2; ++s) {
        const char* sp = WcB + (size_t)s * 8192;
        char* lb = LB + s * 8192;
        gl_lds16(sp + lo, lb + ld);
        gl_lds16(sp + 1024 + lo, lb + 1024 + ld);
    }
    int r0 = wid * 32 + (lane & 15);
    int kgrp = lane >> 4;
    floatx4 acc[2][7] = {};

    for (int ks = 0; ks < 128; ++ks) {
        int buf = ks & 3;
        // A-fragments (static tiles, independent of Bs)
        int i = ks >> 1;
        int ch = (ks & 1) * 4 + kgrp;
        _Float16 h0 = hTT[i >> 3][r0][i & 7];
        _Float16 h1 = hTT[i >> 3][r0 + 16][i & 7];
        H8u t0u, t1u, a0, a1;
        t0u.v8 = *(const half8*)&tT[ch][r0][0];
        t1u.v8 = *(const half8*)&tT[ch][r0 + 16][0];
        half2v h02 = { h0, h0 }, h12 = { h1, h1 };
        #pragma unroll
        for (int q = 0; q < 4; ++q) {
            a0.v2[q] = h02 * t0u.v2[q];
            a1.v2[q] = h12 * t1u.v2[q];
        }
        if (ks < 126) {
            const char* sp = WcB + ((size_t)(ks + 2) << 13);
            char* lb = LB + ((ks + 2) & 3) * 8192;
            gl_lds16(sp + lo, lb + ld);
            gl_lds16(sp + 1024 + lo, lb + 1024 + ld);
            WAITVM(4);
        } else if (ks == 126) { WAITVM(2); } else { WAITVM(0); }
        barrier_raw();
        const half8* bp = (const half8*)(LB + buf * 8192) + lane;
        __builtin_amdgcn_s_setprio(1);
        #pragma unroll
        for (int rt = 0; rt < 7; ++rt) {
            half8 bv = bp[rt * 64];
            acc[0][rt] = __builtin_amdgcn_mfma_f32_16x16x32_f16(a0.v8, bv, acc[0][rt], 0, 0, 0);
            acc[1][rt] = __builtin_amdgcn_mfma_f32_16x16x32_f16(a1.v8, bv, acc[1][rt], 0, 0, 0);
        }
        __builtin_amdgcn_s_setprio(0);
    }
    int rb = lane & 15, u = lane >> 4;
    #pragma unroll
    for (int rs = 0; rs < 2; ++rs) {
        int nbase = n0 + wid * 32 + rs * 16 + u * 4;
        #pragma unroll
        for (int rt = 0; rt < 7; ++rt)
            #pragma unroll
            for (int q = 0; q < 4; ++q)
                part[((size_t)g * NROW + nbase + q) * RP + rt * 16 + rb] =
                    (_Float16)acc[rs][rt][q];
    }
}

// ---------------------------------------------------------------------------
// reduce: logits[n,r] = bc[r] + sum_g part[g, rowp(n), r]
// ---------------------------------------------------------------------------
__global__ __launch_bounds__(256) void k_reduce(
        const _Float16* __restrict__ part, const float* __restrict__ bc,
        float* __restrict__ out) {
    int idx = blockIdx.x * 256 + threadIdx.x;
    if (idx >= NN * RR) return;
    int n = idx / RR;
    int r = idx - n * RR;
    int b = n / PP, p = n - b * PP;
    size_t rowp = (size_t)b * PPAD + p;
    float s = bc[r];
    #pragma unroll
    for (int g = 0; g < GG; ++g)
        s += (float)part[((size_t)g * NROW + rowp) * RP + r];
    out[idx] = s;
}

// ---------------------------------------------------------------------------
extern "C" void kernel_launch(void* const* d_in, const int* in_sizes, int n_in,
                              void* d_out, int out_size, void* d_ws, size_t ws_size,
                              hipStream_t stream) {
    const float* hid  = (const float*)d_in[0];
    const float* att  = (const float*)d_in[1];
    const float* am   = (const float*)d_in[2];
    const int*   head = (const int*)d_in[3];
    const int*   tail = (const int*)d_in[4];
    const float* Wh   = (const float*)d_in[5];
    const float* bh   = (const float*)d_in[6];
    const float* Wt   = (const float*)d_in[7];
    const float* bt   = (const float*)d_in[8];
    const float* Wc   = (const float*)d_in[9];
    const float* bc   = (const float*)d_in[10];
    float* out = (float*)d_out;

    // ---- workspace (~56 MB; part aliases buffers dead before k_logits) ----
    char* w = (char*)d_ws;
    _Float16* Wcp = (_Float16*)w;  w += (size_t)GG * 128 * 8 * 64 * 8 * 2;  // 12.58 MB
    _Float16* Vhf = (_Float16*)w;  w += (size_t)BB * 786432 * 2;            //  6.29 MB
    _Float16* Vtf = (_Float16*)w;  w += (size_t)BB * 786432 * 2;
    _Float16* hbv = (_Float16*)w;  w += (size_t)NROW * HH * 2;              //  6.29 MB
    _Float16* tbv = (_Float16*)w;  w += (size_t)NROW * HH * 2;
    float* Fht      = (float*)w;   w += (size_t)2 * BB * EE * HH * 4;       //  0.79 MB
    float* ent_feat = (float*)w;   w += (size_t)BB * EE * HH * 4;
    float* ent_attn = (float*)w;   w += (size_t)BB * EE * LL * 4;
    char* alias = w;
    _Float16* hidb  = (_Float16*)alias;                                     //  6.29 MB
    _Float16* Whf   = (_Float16*)(alias + 6291456);                         //  1.18 MB
    _Float16* Wtf   = (_Float16*)(alias + 6291456 + 1179648);
    _Float16* pairw = (_Float16*)(alias + 6291456 + 2 * 1179648);           //  8.39 MB
    _Float16* part  = (_Float16*)alias;  // 11.01 MB, overlaps hidb/Whf/Wtf/pairw-prefix:
                                         // all last-read before k_logits writes (stream order)

    k_stage0<<<5440, 256, 0, stream>>>(hid, att, head, tail, Wh, Wt, Wc,
                                       hidb, Whf, Wtf, Wcp, ent_feat, ent_attn);
    k_stage1<<<4192, 256, 0, stream>>>(ent_attn, am, ent_feat, Wh, bh, Wt, bt, pairw, Fht);
    k_vgemm<<<768, 128, 0, stream>>>(hidb, Whf, Wtf, Vhf, Vtf);
    k_proj_mfma<<<768, 128, 0, stream>>>(pairw, Vhf, Vtf, Fht, hbv, tbv);
    k_logits_mfma<<<384, 256, 0, stream>>>(hbv, tbv, Wcp, part);
    k_reduce<<<1504, 256, 0, stream>>>(part, bc, out);
}